// Round 15
// baseline (322.287 us; speedup 1.0000x reference)
//
#include <hip/hip_runtime.h>
#include <hip/hip_bf16.h>
#include <math.h>

#define NN 20000
#define EE 320000
#define FXX 256
#define FWW 128
#define NH 4

typedef __attribute__((ext_vector_type(8))) short short8v;
typedef __attribute__((ext_vector_type(4))) float f32x4;

static __device__ __forceinline__ float bf2f(unsigned short s) {
    unsigned int u = ((unsigned int)s) << 16;
    return __builtin_bit_cast(float, u);
}

static __device__ __forceinline__ unsigned short f2bf_u16(float f) {
    unsigned int u = __builtin_bit_cast(unsigned int, f);
    unsigned int r = 0x7fffu + ((u >> 16) & 1u);
    return (unsigned short)((u + r) >> 16);
}

// ---------------------------------------------------------------- w~ = W_h @ a (score projection vectors), fp32
struct WscItem { const float* W; const float* as_; const float* ad_; int Fin; };
struct WscParams { WscItem t[4]; };

__global__ __launch_bounds__(256) void wsc_kernel(WscParams p, float* __restrict__ wsc)
{
    int L = blockIdx.z;
    WscItem it = p.t[L];
    int wid = threadIdx.x >> 6, lane = threadIdx.x & 63;
    int r = blockIdx.x * 4 + wid;
    if (r >= it.Fin * 4) return;
    int h = r / it.Fin, k = r - h * it.Fin;
    float2 w2 = *(const float2*)(it.W + ((size_t)(h * it.Fin + k)) * 128 + 2 * lane);
    float2 s2 = *(const float2*)(it.as_ + h * 128 + 2 * lane);
    float2 d2 = *(const float2*)(it.ad_ + h * 128 + 2 * lane);
    float vs = w2.x * s2.x + w2.y * s2.y;
    float vd = w2.x * d2.x + w2.y * d2.y;
    #pragma unroll
    for (int o = 32; o; o >>= 1) { vs += __shfl_xor(vs, o); vd += __shfl_xor(vd, o); }
    if (lane == 0) {
        wsc[(size_t)L * 2048 + h * 256 + k] = vs;
        wsc[(size_t)L * 2048 + (4 + h) * 256 + k] = vd;
    }
}

// ---------------------------------------------------------------- combined GEMM weights
struct WcItem { const float* W; const float* R; __hip_bfloat16* dst; int Fin; int KK; int total; };
struct WcParams { WcItem t[4]; };

__global__ __launch_bounds__(256) void wcomb_kernel(WcParams p)
{
    WcItem it = p.t[blockIdx.z];
    int idx = blockIdx.x * 256 + threadIdx.x;
    if (idx >= it.total) return;
    int c = idx / it.KK;
    int k5 = idx - c * it.KK;
    int f4 = it.Fin * 4;
    float v;
    if (k5 < f4) {
        int h = k5 / it.Fin, k = k5 - h * it.Fin;
        v = 0.25f * it.W[((size_t)(h * it.Fin + k)) * 128 + c];
    } else {
        v = it.R[(size_t)(k5 - f4) * 128 + c];
    }
    it.dst[(size_t)c * it.KK + k5] = __float2bfloat16(v);
}

// ---------------------------------------------------------------- fused cast + scores (both inputs, one dispatch)
template<int CF>
static __device__ __forceinline__ void cast_score_body(const float* __restrict__ Xf,
                                                       __hip_bfloat16* __restrict__ Xb,
                                                       const float* __restrict__ wsc,
                                                       float* __restrict__ ssrc,
                                                       float* __restrict__ sdst)
{
    const int Fin = CF * 64;
    int wid = threadIdx.x >> 6, lane = threadIdx.x & 63;
    int n = blockIdx.x * 4 + wid;
    if (n >= NN) return;
    int c0 = lane * CF;
    float xv[CF];
    #pragma unroll
    for (int i = 0; i < CF; ++i) xv[i] = Xf[(size_t)n * Fin + c0 + i];
    union { unsigned u[CF / 2]; unsigned short s[CF]; } pk;
    #pragma unroll
    for (int i = 0; i < CF; ++i) pk.s[i] = f2bf_u16(xv[i]);
    #pragma unroll
    for (int w = 0; w < CF / 2; ++w)
        *(unsigned*)(Xb + (size_t)n * Fin + c0 + w * 2) = pk.u[w];
    float acc[8];
    #pragma unroll
    for (int j = 0; j < 8; ++j) {
        const float* w = wsc + j * 256 + c0;
        float s = 0.f;
        #pragma unroll
        for (int i = 0; i < CF; ++i) s += xv[i] * w[i];
        acc[j] = s;
    }
    #pragma unroll
    for (int o = 32; o; o >>= 1)
        #pragma unroll
        for (int j = 0; j < 8; ++j) acc[j] += __shfl_xor(acc[j], o);
    if (lane == 0) {
        *(float4*)(ssrc + (size_t)n * 4) = make_float4(acc[0], acc[1], acc[2], acc[3]);
        *(float4*)(sdst + (size_t)n * 4) = make_float4(acc[4], acc[5], acc[6], acc[7]);
    }
}

struct CSPair {
    const float* Xf[2]; __hip_bfloat16* Xb[2];
    const float* wsc[2]; float* ssrc[2]; float* sdst[2];
};

__global__ __launch_bounds__(256) void cast_score_pair(CSPair p)
{
    if (blockIdx.y == 0)
        cast_score_body<4>(p.Xf[0], p.Xb[0], p.wsc[0], p.ssrc[0], p.sdst[0]);
    else
        cast_score_body<2>(p.Xf[1], p.Xb[1], p.wsc[1], p.ssrc[1], p.sdst[1]);
}

// ---------------------------------------------------------------- CSR build
__global__ __launch_bounds__(256) void hist_kernel(const int* __restrict__ src, int* __restrict__ cnt)
{
    int i = blockIdx.x * blockDim.x + threadIdx.x;
    if (i < EE) atomicAdd(&cnt[src[i]], 1);
}

__global__ __launch_bounds__(1024) void scan_kernel(const int* __restrict__ cnt, int* __restrict__ row_ptr)
{
    __shared__ int lds[1024];
    int t = threadIdx.x;
    const int CH = 20;
    int start = t * CH, end = start + CH; if (end > NN) end = NN;
    int sum = 0;
    if (start < NN) for (int i = start; i < end; ++i) sum += cnt[i];
    lds[t] = sum;
    __syncthreads();
    for (int o = 1; o < 1024; o <<= 1) {
        int v = (t >= o) ? lds[t - o] : 0;
        __syncthreads();
        lds[t] += v;
        __syncthreads();
    }
    int run = lds[t] - sum;
    if (start < NN) for (int i = start; i < end; ++i) { row_ptr[i] = run; run += cnt[i]; }
    if (t == 1023) row_ptr[NN] = lds[1023];
}

__global__ __launch_bounds__(256) void scatter_kernel(const int* __restrict__ src,
                                                      const int* __restrict__ dst,
                                                      const int* __restrict__ row_ptr,
                                                      int* __restrict__ off,
                                                      int* __restrict__ csr_dst)
{
    int i = blockIdx.x * blockDim.x + threadIdx.x;
    if (i >= EE) return;
    int s = src[i];
    int p = row_ptr[s] + atomicAdd(&off[s], 1);
    csr_dst[p] = dst[i];
}

// ---------------------------------------------------------------- FUSED softmax + aggregate body
template<int CF>
static __device__ __forceinline__ void agg_body(const __hip_bfloat16* __restrict__ Xb,
                                                const float* __restrict__ ssrc,
                                                const float* __restrict__ sdst,
                                                const int* __restrict__ row_ptr,
                                                const int* __restrict__ csr_dst,
                                                __hip_bfloat16* __restrict__ Cat)
{
    const int Fin = CF * 64, F4 = 4 * Fin;
    int wid = threadIdx.x >> 6, lane = threadIdx.x & 63;
    int n = blockIdx.x * 4 + wid;
    if (n >= NN) return;
    int r0 = row_ptr[n], r1 = row_ptr[n + 1];
    int deg = r1 - r0;

    float acc[4][CF] = {};

    if (deg > 0) {
        float4 sn = *(const float4*)(ssrc + (size_t)n * 4);
        auto comp_e = [&](int s, int& dout) -> float4 {
            int d = csr_dst[r0 + s];
            dout = d;
            float4 sd = *(const float4*)(sdst + (size_t)d * 4);
            float4 e; float v;
            v = sn.x + sd.x; e.x = v >= 0.f ? v : 0.2f * v;
            v = sn.y + sd.y; e.y = v >= 0.f ? v : 0.2f * v;
            v = sn.z + sd.z; e.z = v >= 0.f ? v : 0.2f * v;
            v = sn.w + sd.w; e.w = v >= 0.f ? v : 0.2f * v;
            return e;
        };

        float4 e0 = make_float4(-1e30f, -1e30f, -1e30f, -1e30f);
        int d0 = 0;
        if (lane < deg) e0 = comp_e(lane, d0);
        float4 m = e0;
        for (int s = lane + 64; s < deg; s += 64) {
            int dt; float4 ev = comp_e(s, dt);
            m.x = fmaxf(m.x, ev.x); m.y = fmaxf(m.y, ev.y);
            m.z = fmaxf(m.z, ev.z); m.w = fmaxf(m.w, ev.w);
        }
        #pragma unroll
        for (int o = 32; o; o >>= 1) {
            m.x = fmaxf(m.x, __shfl_xor(m.x, o));
            m.y = fmaxf(m.y, __shfl_xor(m.y, o));
            m.z = fmaxf(m.z, __shfl_xor(m.z, o));
            m.w = fmaxf(m.w, __shfl_xor(m.w, o));
        }
        float4 p0 = make_float4(0.f, 0.f, 0.f, 0.f);
        if (lane < deg) {
            p0.x = expf(e0.x - m.x); p0.y = expf(e0.y - m.y);
            p0.z = expf(e0.z - m.z); p0.w = expf(e0.w - m.w);
        }
        float4 den = p0;
        for (int s = lane + 64; s < deg; s += 64) {
            int dt; float4 ev = comp_e(s, dt);
            den.x += expf(ev.x - m.x); den.y += expf(ev.y - m.y);
            den.z += expf(ev.z - m.z); den.w += expf(ev.w - m.w);
        }
        #pragma unroll
        for (int o = 32; o; o >>= 1) {
            den.x += __shfl_xor(den.x, o); den.y += __shfl_xor(den.y, o);
            den.z += __shfl_xor(den.z, o); den.w += __shfl_xor(den.w, o);
        }
        den.x = 1.f / (den.x + 1e-16f); den.y = 1.f / (den.y + 1e-16f);
        den.z = 1.f / (den.z + 1e-16f); den.w = 1.f / (den.w + 1e-16f);

        float4 a0;
        a0.x = p0.x * den.x; a0.y = p0.y * den.y;
        a0.z = p0.z * den.z; a0.w = p0.w * den.w;

        int cnt0 = min(deg, 64);
        int last = cnt0 - 1;
        for (int base = 0; base < cnt0; base += 4) {
            int j1 = min(base + 1, last), j2 = min(base + 2, last), j3 = min(base + 3, last);
            int dv0 = __shfl(d0, base), dv1 = __shfl(d0, j1);
            int dv2 = __shfl(d0, j2),   dv3 = __shfl(d0, j3);
            union U { unsigned u[CF / 2]; unsigned short s[CF]; };
            U l0, l1, l2, l3;
            #pragma unroll
            for (int w = 0; w < CF / 2; ++w)
                l0.u[w] = *(const unsigned*)(Xb + (size_t)dv0 * Fin + lane * CF + w * 2);
            #pragma unroll
            for (int w = 0; w < CF / 2; ++w)
                l1.u[w] = *(const unsigned*)(Xb + (size_t)dv1 * Fin + lane * CF + w * 2);
            #pragma unroll
            for (int w = 0; w < CF / 2; ++w)
                l2.u[w] = *(const unsigned*)(Xb + (size_t)dv2 * Fin + lane * CF + w * 2);
            #pragma unroll
            for (int w = 0; w < CF / 2; ++w)
                l3.u[w] = *(const unsigned*)(Xb + (size_t)dv3 * Fin + lane * CF + w * 2);

            {
                float ax = __shfl(a0.x, base), ay = __shfl(a0.y, base);
                float az = __shfl(a0.z, base), aw = __shfl(a0.w, base);
                #pragma unroll
                for (int i = 0; i < CF; ++i) {
                    float xv = bf2f(l0.s[i]);
                    acc[0][i] += ax * xv; acc[1][i] += ay * xv;
                    acc[2][i] += az * xv; acc[3][i] += aw * xv;
                }
            }
            if (base + 1 < cnt0) {
                float ax = __shfl(a0.x, j1), ay = __shfl(a0.y, j1);
                float az = __shfl(a0.z, j1), aw = __shfl(a0.w, j1);
                #pragma unroll
                for (int i = 0; i < CF; ++i) {
                    float xv = bf2f(l1.s[i]);
                    acc[0][i] += ax * xv; acc[1][i] += ay * xv;
                    acc[2][i] += az * xv; acc[3][i] += aw * xv;
                }
            }
            if (base + 2 < cnt0) {
                float ax = __shfl(a0.x, j2), ay = __shfl(a0.y, j2);
                float az = __shfl(a0.z, j2), aw = __shfl(a0.w, j2);
                #pragma unroll
                for (int i = 0; i < CF; ++i) {
                    float xv = bf2f(l2.s[i]);
                    acc[0][i] += ax * xv; acc[1][i] += ay * xv;
                    acc[2][i] += az * xv; acc[3][i] += aw * xv;
                }
            }
            if (base + 3 < cnt0) {
                float ax = __shfl(a0.x, j3), ay = __shfl(a0.y, j3);
                float az = __shfl(a0.z, j3), aw = __shfl(a0.w, j3);
                #pragma unroll
                for (int i = 0; i < CF; ++i) {
                    float xv = bf2f(l3.s[i]);
                    acc[0][i] += ax * xv; acc[1][i] += ay * xv;
                    acc[2][i] += az * xv; acc[3][i] += aw * xv;
                }
            }
        }

        for (int r = r0 + 64; r < r1; r += 64) {
            int cnt = min(64, r1 - r);
            int d = 0;
            float4 a4 = make_float4(0.f, 0.f, 0.f, 0.f);
            if (r + lane < r1) {
                int dt;
                float4 ev = comp_e(r - r0 + lane, dt);
                d = dt;
                a4.x = expf(ev.x - m.x) * den.x; a4.y = expf(ev.y - m.y) * den.y;
                a4.z = expf(ev.z - m.z) * den.z; a4.w = expf(ev.w - m.w) * den.w;
            }
            for (int j = 0; j < cnt; ++j) {
                int ddv = __shfl(d, j);
                float ax = __shfl(a4.x, j), ay = __shfl(a4.y, j);
                float az = __shfl(a4.z, j), aw = __shfl(a4.w, j);
                union { unsigned u[CF / 2]; unsigned short s[CF]; } ld;
                #pragma unroll
                for (int w = 0; w < CF / 2; ++w)
                    ld.u[w] = *(const unsigned*)(Xb + (size_t)ddv * Fin + lane * CF + w * 2);
                #pragma unroll
                for (int i = 0; i < CF; ++i) {
                    float xv = bf2f(ld.s[i]);
                    acc[0][i] += ax * xv; acc[1][i] += ay * xv;
                    acc[2][i] += az * xv; acc[3][i] += aw * xv;
                }
            }
        }
    }

    __hip_bfloat16* crow = Cat + (size_t)n * F4;
    #pragma unroll
    for (int h = 0; h < 4; ++h) {
        union { unsigned u[CF / 2]; unsigned short s[CF]; } pk;
        #pragma unroll
        for (int i = 0; i < CF; ++i) pk.s[i] = f2bf_u16(acc[h][i]);
        #pragma unroll
        for (int w = 0; w < CF / 2; ++w)
            *(unsigned*)(crow + h * Fin + lane * CF + w * 2) = pk.u[w];
    }
}

struct AggPair {
    const __hip_bfloat16* Xb[2];
    const float* ssrc[2]; const float* sdst[2];
    __hip_bfloat16* Cat[2];
};

template<int CF0, int CF1>
__global__ __launch_bounds__(256) void agg_pair_kernel(AggPair p,
                                                       const int* __restrict__ row_ptr,
                                                       const int* __restrict__ csr_dst)
{
    if (blockIdx.y == 0)
        agg_body<CF0>(p.Xb[0], p.ssrc[0], p.sdst[0], row_ptr, csr_dst, p.Cat[0]);
    else
        agg_body<CF1>(p.Xb[1], p.ssrc[1], p.sdst[1], row_ptr, csr_dst, p.Cat[1]);
}

// ---------------------------------------------------------------- MFMA GEMM + ELU + SE-pool + optional next scores (bf16-only output)
struct GemmArgs {
    const __hip_bfloat16 *Cat, *Xb, *Wct;
    __hip_bfloat16* xbout;
    const float* wscN; float *ssrcN, *sdstN;
    int F4, FIN, ch;
};
struct GemmPair { GemmArgs g[2]; };

__global__ __launch_bounds__(256) void gemm_pair_kernel(GemmPair p, float* __restrict__ sums)
{
    GemmArgs a = (blockIdx.y == 0) ? p.g[0] : p.g[1];
    const int F4 = a.F4, FIN = a.FIN;
    const int KK = F4 + FIN;
    const int BK = 64;
    const int NIT = KK / BK;
    __shared__ short As[2][32 * 72];
    __shared__ short Bs[2][128 * 72];
    __shared__ float ls[4];
    __shared__ float sred[4][4][4][8];

    int tid = threadIdx.x, lane = tid & 63, wid = tid >> 6;
    int wr = wid >> 1, wc = wid & 1;
    int ar = lane & 15, kg = lane >> 4;
    int row0 = blockIdx.x * 32;

    int a_row = tid >> 3, a_seg = tid & 7;
    int b_col = tid >> 1, b_seg0 = (tid & 1) * 4;

    const __hip_bfloat16* AgC = a.Cat + (size_t)(row0 + a_row) * F4 + a_seg * 8;
    const __hip_bfloat16* AgX = a.Xb + (size_t)(row0 + a_row) * FIN + a_seg * 8;
    const __hip_bfloat16* Bg = a.Wct + (size_t)b_col * KK + b_seg0 * 8;

    short8v fa, fb0, fb1, fb2, fb3;
    f32x4 acc[4] = {};

    fa  = *(const short8v*)(AgC);
    fb0 = *(const short8v*)(Bg);
    fb1 = *(const short8v*)(Bg + 8);
    fb2 = *(const short8v*)(Bg + 16);
    fb3 = *(const short8v*)(Bg + 24);
    *(short8v*)(&As[0][a_row * 72 + a_seg * 8]) = fa;
    *(short8v*)(&Bs[0][b_col * 72 + (b_seg0 + 0) * 8]) = fb0;
    *(short8v*)(&Bs[0][b_col * 72 + (b_seg0 + 1) * 8]) = fb1;
    *(short8v*)(&Bs[0][b_col * 72 + (b_seg0 + 2) * 8]) = fb2;
    *(short8v*)(&Bs[0][b_col * 72 + (b_seg0 + 3) * 8]) = fb3;

    int cur = 0;
    for (int it = 0; it < NIT; ++it) {
        if (it + 1 < NIT) {
            int kb = (it + 1) * BK;
            fa  = (kb < F4) ? *(const short8v*)(AgC + kb) : *(const short8v*)(AgX + (kb - F4));
            fb0 = *(const short8v*)(Bg + kb);
            fb1 = *(const short8v*)(Bg + kb + 8);
            fb2 = *(const short8v*)(Bg + kb + 16);
            fb3 = *(const short8v*)(Bg + kb + 24);
        }
        __syncthreads();
        #pragma unroll
        for (int ks = 0; ks < 2; ++ks) {
            short8v av = *(const short8v*)(&As[cur][(wr * 16 + ar) * 72 + ks * 32 + kg * 8]);
            #pragma unroll
            for (int nb = 0; nb < 4; ++nb) {
                short8v bv = *(const short8v*)(&Bs[cur][(wc * 64 + nb * 16 + ar) * 72 + ks * 32 + kg * 8]);
                acc[nb] = __builtin_amdgcn_mfma_f32_16x16x32_bf16(av, bv, acc[nb], 0, 0, 0);
            }
        }
        if (it + 1 < NIT) {
            int nb2 = cur ^ 1;
            *(short8v*)(&As[nb2][a_row * 72 + a_seg * 8]) = fa;
            *(short8v*)(&Bs[nb2][b_col * 72 + (b_seg0 + 0) * 8]) = fb0;
            *(short8v*)(&Bs[nb2][b_col * 72 + (b_seg0 + 1) * 8]) = fb1;
            *(short8v*)(&Bs[nb2][b_col * 72 + (b_seg0 + 2) * 8]) = fb2;
            *(short8v*)(&Bs[nb2][b_col * 72 + (b_seg0 + 3) * 8]) = fb3;
        }
        cur ^= 1;
    }

    float lsum = 0.f;
    float vpost[4][4];
    int rsub = (lane >> 4) * 4;
    #pragma unroll
    for (int nb = 0; nb < 4; ++nb) {
        int col = wc * 64 + nb * 16 + ar;
        #pragma unroll
        for (int r = 0; r < 4; ++r) {
            int row = row0 + wr * 16 + rsub + r;
            float v = acc[nb][r];
            v = v > 0.f ? v : expm1f(v);
            vpost[nb][r] = v;
            lsum += v;
            a.xbout[(size_t)row * 128 + col] = __float2bfloat16(v);
        }
    }
    #pragma unroll
    for (int o = 32; o; o >>= 1) lsum += __shfl_xor(lsum, o);
    if (lane == 0) ls[wid] = lsum;

    bool dosc = a.wscN != nullptr;
    if (dosc) {
        float sc[4][8] = {};
        #pragma unroll
        for (int j = 0; j < 8; ++j) {
            #pragma unroll
            for (int nb = 0; nb < 4; ++nb) {
                float wv = a.wscN[j * 256 + wc * 64 + nb * 16 + ar];
                #pragma unroll
                for (int r = 0; r < 4; ++r) sc[r][j] += vpost[nb][r] * wv;
            }
        }
        #pragma unroll
        for (int o = 8; o; o >>= 1)
            #pragma unroll
            for (int r = 0; r < 4; ++r)
                #pragma unroll
                for (int j = 0; j < 8; ++j) sc[r][j] += __shfl_xor(sc[r][j], o);
        if (ar == 0) {
            int grp = lane >> 4;
            #pragma unroll
            for (int r = 0; r < 4; ++r)
                #pragma unroll
                for (int j = 0; j < 8; ++j) sred[wid][grp][r][j] = sc[r][j];
        }
    }
    __syncthreads();
    if (tid == 0) atomicAdd(&sums[a.ch], ls[0] + ls[1] + ls[2] + ls[3]);
    if (dosc) {
        int row_local = tid >> 3, j = tid & 7;
        int w_r = row_local >> 4, grp = (row_local >> 2) & 3, r = row_local & 3;
        float total = sred[w_r * 2 + 0][grp][r][j] + sred[w_r * 2 + 1][grp][r][j];
        int row = row0 + row_local;
        if (j < 4) a.ssrcN[(size_t)row * 4 + j] = total;
        else       a.sdstN[(size_t)row * 4 + (j - 4)] = total;
    }
}

// ---------------------------------------------------------------- final: inline SE MLP + relu(att*x) conv, bf16 inputs, 2 elems/thread
__global__ __launch_bounds__(256) void final_kernel(const __hip_bfloat16* __restrict__ x1,
                                                    const __hip_bfloat16* __restrict__ x2,
                                                    const __hip_bfloat16* __restrict__ d1,
                                                    const __hip_bfloat16* __restrict__ d2,
                                                    const float* __restrict__ sums,
                                                    const float* __restrict__ fc1w, const float* __restrict__ fc1b,
                                                    const float* __restrict__ fc2w, const float* __restrict__ fc2b,
                                                    const float* __restrict__ convw,
                                                    const float* __restrict__ convb,
                                                    float* __restrict__ out)
{
    // inline SE MLP (tiny; every thread computes it)
    float att[4];
    {
        float avg[4];
        #pragma unroll
        for (int c = 0; c < 4; ++c) avg[c] = sums[c] * (1.f / (NN * 128.f));
        float z[20];
        #pragma unroll
        for (int j = 0; j < 20; ++j) {
            float v = fc1b[j];
            #pragma unroll
            for (int c = 0; c < 4; ++c) v += avg[c] * fc1w[c * 20 + j];
            z[j] = v;
        }
        #pragma unroll
        for (int c = 0; c < 4; ++c) {
            float v = fc2b[c];
            #pragma unroll
            for (int j = 0; j < 20; ++j) v += z[j] * fc2w[j * 4 + c];
            att[c] = 1.f / (1.f + expf(-v));
        }
    }
    int i = (blockIdx.x * 256 + threadIdx.x) * 2;
    if (i >= NN * 128) return;
    unsigned u1 = *(const unsigned*)(x1 + i);
    unsigned u2 = *(const unsigned*)(x2 + i);
    unsigned u3 = *(const unsigned*)(d1 + i);
    unsigned u4 = *(const unsigned*)(d2 + i);
    float w0 = convw[0], w1 = convw[1], w2 = convw[2], w3 = convw[3];
    float cb = convb[0];
    float2 r;
    r.x = cb + w0 * fmaxf(att[0] * bf2f((unsigned short)(u1 & 0xffff)), 0.f)
             + w1 * fmaxf(att[1] * bf2f((unsigned short)(u2 & 0xffff)), 0.f)
             + w2 * fmaxf(att[2] * bf2f((unsigned short)(u3 & 0xffff)), 0.f)
             + w3 * fmaxf(att[3] * bf2f((unsigned short)(u4 & 0xffff)), 0.f);
    r.y = cb + w0 * fmaxf(att[0] * bf2f((unsigned short)(u1 >> 16)), 0.f)
             + w1 * fmaxf(att[1] * bf2f((unsigned short)(u2 >> 16)), 0.f)
             + w2 * fmaxf(att[2] * bf2f((unsigned short)(u3 >> 16)), 0.f)
             + w3 * fmaxf(att[3] * bf2f((unsigned short)(u4 >> 16)), 0.f);
    *(float2*)(out + i) = r;
}

// ---------------------------------------------------------------- host
extern "C" void kernel_launch(void* const* d_in, const int* in_sizes, int n_in,
                              void* d_out, int out_size, void* d_ws, size_t ws_size,
                              hipStream_t stream)
{
    (void)in_sizes; (void)n_in; (void)out_size; (void)ws_size;
    const float* x    = (const float*)d_in[0];
    const float* dat  = (const float*)d_in[1];
    const float* W1   = (const float*)d_in[2];
    const float* a1s  = (const float*)d_in[3];
    const float* a1d  = (const float*)d_in[4];
    const float* R1   = (const float*)d_in[5];
    const float* W2   = (const float*)d_in[6];
    const float* a2s  = (const float*)d_in[7];
    const float* a2d  = (const float*)d_in[8];
    const float* R2   = (const float*)d_in[9];
    const float* Wd1  = (const float*)d_in[10];
    const float* ad1s = (const float*)d_in[11];
    const float* ad1d = (const float*)d_in[12];
    const float* Rd1  = (const float*)d_in[13];
    const float* Wd2  = (const float*)d_in[14];
    const float* ad2s = (const float*)d_in[15];
    const float* ad2d = (const float*)d_in[16];
    const float* Rd2  = (const float*)d_in[17];
    const float* fc1w = (const float*)d_in[18];
    const float* fc1b = (const float*)d_in[19];
    const float* fc2w = (const float*)d_in[20];
    const float* fc2b = (const float*)d_in[21];
    const float* convw= (const float*)d_in[22];
    const float* convb= (const float*)d_in[23];
    const int*   eidx = (const int*)d_in[24];
    const int* esrc = eidx;
    const int* edst = eidx + EE;
    float* out = (float*)d_out;

    char* base = (char*)d_ws;
    size_t woff = 0;
    auto alloc = [&](size_t bytes) -> void* {
        void* p = base + woff;
        woff = (woff + bytes + 255) & ~(size_t)255;
        return p;
    };
    __hip_bfloat16* Cat0 = (__hip_bfloat16*)alloc((size_t)NN * 1024 * 2);
    __hip_bfloat16* Cat2 = (__hip_bfloat16*)alloc((size_t)NN * 512 * 2);
    __hip_bfloat16* XbX   = (__hip_bfloat16*)alloc((size_t)NN * FXX * 2);
    __hip_bfloat16* XbDat = (__hip_bfloat16*)alloc((size_t)NN * FWW * 2);
    __hip_bfloat16* Xb1   = (__hip_bfloat16*)alloc((size_t)NN * 128 * 2);
    __hip_bfloat16* XbD1  = (__hip_bfloat16*)alloc((size_t)NN * 128 * 2);
    __hip_bfloat16* Xb2   = (__hip_bfloat16*)alloc((size_t)NN * 128 * 2);
    __hip_bfloat16* XbD2  = (__hip_bfloat16*)alloc((size_t)NN * 128 * 2);
    float* Wsc   = (float*)alloc((size_t)4 * 2048 * 4);
    __hip_bfloat16* Wct0 = (__hip_bfloat16*)alloc((size_t)128 * 1280 * 2);
    __hip_bfloat16* Wct1 = (__hip_bfloat16*)alloc((size_t)128 * 640 * 2);
    __hip_bfloat16* Wct2 = (__hip_bfloat16*)alloc((size_t)128 * 640 * 2);
    __hip_bfloat16* Wct3 = (__hip_bfloat16*)alloc((size_t)128 * 640 * 2);
    float* SsrcX = (float*)alloc((size_t)NN * 4 * 4);
    float* SdstX = (float*)alloc((size_t)NN * 4 * 4);
    float* Ssrc1 = (float*)alloc((size_t)NN * 4 * 4);
    float* Sdst1 = (float*)alloc((size_t)NN * 4 * 4);
    float* SsrcD = (float*)alloc((size_t)NN * 4 * 4);
    float* SdstD = (float*)alloc((size_t)NN * 4 * 4);
    float* Ssrc3 = (float*)alloc((size_t)NN * 4 * 4);
    float* Sdst3 = (float*)alloc((size_t)NN * 4 * 4);
    int* RowPtr  = (int*)alloc((size_t)(NN + 1) * 4);
    int* Cnt     = (int*)alloc((size_t)NN * 4);
    int* Off     = (int*)alloc((size_t)NN * 4);
    int* CsrDst  = (int*)alloc((size_t)EE * 4);
    float* Sums  = (float*)alloc(16);

    // setup
    {
        WscParams WP;
        WP.t[0] = { W1,  a1s,  a1d,  FXX };
        WP.t[1] = { W2,  a2s,  a2d,  FWW };
        WP.t[2] = { Wd1, ad1s, ad1d, FWW };
        WP.t[3] = { Wd2, ad2s, ad2d, FWW };
        wsc_kernel<<<dim3(256, 1, 4), 256, 0, stream>>>(WP, Wsc);
        WcParams CP;
        CP.t[0] = { W1,  R1,  Wct0, FXX, 1280, 128 * 1280 };
        CP.t[1] = { W2,  R2,  Wct1, FWW, 640,  128 * 640 };
        CP.t[2] = { Wd1, Rd1, Wct2, FWW, 640,  128 * 640 };
        CP.t[3] = { Wd2, Rd2, Wct3, FWW, 640,  128 * 640 };
        wcomb_kernel<<<dim3(640, 1, 4), 256, 0, stream>>>(CP);
        CSPair CS;
        CS.Xf[0] = x;   CS.Xb[0] = XbX;   CS.wsc[0] = Wsc;            CS.ssrc[0] = SsrcX; CS.sdst[0] = SdstX;
        CS.Xf[1] = dat; CS.Xb[1] = XbDat; CS.wsc[1] = Wsc + 2 * 2048; CS.ssrc[1] = SsrcD; CS.sdst[1] = SdstD;
        cast_score_pair<<<dim3((NN + 3) / 4, 2), 256, 0, stream>>>(CS);
    }
    hipMemsetAsync(Cnt, 0, (size_t)NN * 4, stream);
    hipMemsetAsync(Off, 0, (size_t)NN * 4, stream);
    hipMemsetAsync(Sums, 0, 16, stream);
    hist_kernel<<<(EE + 255) / 256, 256, 0, stream>>>(esrc, Cnt);
    scan_kernel<<<1, 1024, 0, stream>>>(Cnt, RowPtr);
    scatter_kernel<<<(EE + 255) / 256, 256, 0, stream>>>(esrc, edst, RowPtr, Off, CsrDst);

    // stage A: agg layers {0, 2}
    {
        AggPair AP;
        AP.Xb[0] = XbX;   AP.ssrc[0] = SsrcX; AP.sdst[0] = SdstX; AP.Cat[0] = Cat0;
        AP.Xb[1] = XbDat; AP.ssrc[1] = SsrcD; AP.sdst[1] = SdstD; AP.Cat[1] = Cat2;
        agg_pair_kernel<4, 2><<<dim3((NN + 3) / 4, 2), 256, 0, stream>>>(AP, RowPtr, CsrDst);
    }
    // stage B: gemm layers {0, 2} (+ next-layer scores)
    {
        GemmPair GP;
        GP.g[0] = { Cat0, XbX,   Wct0, Xb1,  Wsc + 1 * 2048, Ssrc1, Sdst1, 1024, 256, 0 };
        GP.g[1] = { Cat2, XbDat, Wct2, XbD1, Wsc + 3 * 2048, Ssrc3, Sdst3, 512,  128, 2 };
        gemm_pair_kernel<<<dim3(NN / 32, 2), 256, 0, stream>>>(GP, Sums);
    }
    // stage C: agg layers {1, 3}
    {
        AggPair AP;
        AP.Xb[0] = Xb1;  AP.ssrc[0] = Ssrc1; AP.sdst[0] = Sdst1; AP.Cat[0] = Cat0;
        AP.Xb[1] = XbD1; AP.ssrc[1] = Ssrc3; AP.sdst[1] = Sdst3; AP.Cat[1] = Cat2;
        agg_pair_kernel<2, 2><<<dim3((NN + 3) / 4, 2), 256, 0, stream>>>(AP, RowPtr, CsrDst);
    }
    // stage D: gemm layers {1, 3}
    {
        GemmPair GP;
        GP.g[0] = { Cat0, Xb1,  Wct1, Xb2,  nullptr, nullptr, nullptr, 512, 128, 1 };
        GP.g[1] = { Cat2, XbD1, Wct3, XbD2, nullptr, nullptr, nullptr, 512, 128, 3 };
        gemm_pair_kernel<<<dim3(NN / 32, 2), 256, 0, stream>>>(GP, Sums);
    }

    final_kernel<<<(NN * 128 / 2 + 255) / 256, 256, 0, stream>>>(Xb1, Xb2, XbD1, XbD2, Sums,
                                                                 fc1w, fc1b, fc2w, fc2b,
                                                                 convw, convb, out);
}

// Round 16
// 321.248 us; speedup vs baseline: 1.0032x; 1.0032x over previous
//
#include <hip/hip_runtime.h>
#include <hip/hip_bf16.h>
#include <math.h>

#define NN 20000
#define EE 320000
#define FXX 256
#define FWW 128
#define NH 4

typedef __attribute__((ext_vector_type(8))) short short8v;
typedef __attribute__((ext_vector_type(4))) float f32x4;

static __device__ __forceinline__ float bf2f(unsigned short s) {
    unsigned int u = ((unsigned int)s) << 16;
    return __builtin_bit_cast(float, u);
}

static __device__ __forceinline__ unsigned short f2bf_u16(float f) {
    unsigned int u = __builtin_bit_cast(unsigned int, f);
    unsigned int r = 0x7fffu + ((u >> 16) & 1u);
    return (unsigned short)((u + r) >> 16);
}

// unpack one dword of 2 bf16 into 2 exact floats (2 VALU ops)
static __device__ __forceinline__ float2 bfpair(unsigned u) {
    float lo = __builtin_bit_cast(float, u << 16);
    float hi = __builtin_bit_cast(float, u & 0xFFFF0000u);
    return make_float2(lo, hi);
}

// ---------------------------------------------------------------- w~ = W_h @ a (score projection vectors), fp32
struct WscItem { const float* W; const float* as_; const float* ad_; int Fin; };
struct WscParams { WscItem t[4]; };

__global__ __launch_bounds__(256) void wsc_kernel(WscParams p, float* __restrict__ wsc)
{
    int L = blockIdx.z;
    WscItem it = p.t[L];
    int wid = threadIdx.x >> 6, lane = threadIdx.x & 63;
    int r = blockIdx.x * 4 + wid;
    if (r >= it.Fin * 4) return;
    int h = r / it.Fin, k = r - h * it.Fin;
    float2 w2 = *(const float2*)(it.W + ((size_t)(h * it.Fin + k)) * 128 + 2 * lane);
    float2 s2 = *(const float2*)(it.as_ + h * 128 + 2 * lane);
    float2 d2 = *(const float2*)(it.ad_ + h * 128 + 2 * lane);
    float vs = w2.x * s2.x + w2.y * s2.y;
    float vd = w2.x * d2.x + w2.y * d2.y;
    #pragma unroll
    for (int o = 32; o; o >>= 1) { vs += __shfl_xor(vs, o); vd += __shfl_xor(vd, o); }
    if (lane == 0) {
        wsc[(size_t)L * 2048 + h * 256 + k] = vs;
        wsc[(size_t)L * 2048 + (4 + h) * 256 + k] = vd;
    }
}

// ---------------------------------------------------------------- combined GEMM weights
struct WcItem { const float* W; const float* R; __hip_bfloat16* dst; int Fin; int KK; int total; };
struct WcParams { WcItem t[4]; };

__global__ __launch_bounds__(256) void wcomb_kernel(WcParams p)
{
    WcItem it = p.t[blockIdx.z];
    int idx = blockIdx.x * 256 + threadIdx.x;
    if (idx >= it.total) return;
    int c = idx / it.KK;
    int k5 = idx - c * it.KK;
    int f4 = it.Fin * 4;
    float v;
    if (k5 < f4) {
        int h = k5 / it.Fin, k = k5 - h * it.Fin;
        v = 0.25f * it.W[((size_t)(h * it.Fin + k)) * 128 + c];
    } else {
        v = it.R[(size_t)(k5 - f4) * 128 + c];
    }
    it.dst[(size_t)c * it.KK + k5] = __float2bfloat16(v);
}

// ---------------------------------------------------------------- fused cast + scores (both inputs, one dispatch)
template<int CF>
static __device__ __forceinline__ void cast_score_body(const float* __restrict__ Xf,
                                                       __hip_bfloat16* __restrict__ Xb,
                                                       const float* __restrict__ wsc,
                                                       float* __restrict__ ssrc,
                                                       float* __restrict__ sdst)
{
    const int Fin = CF * 64;
    int wid = threadIdx.x >> 6, lane = threadIdx.x & 63;
    int n = blockIdx.x * 4 + wid;
    if (n >= NN) return;
    int c0 = lane * CF;
    float xv[CF];
    #pragma unroll
    for (int i = 0; i < CF; ++i) xv[i] = Xf[(size_t)n * Fin + c0 + i];
    union { unsigned u[CF / 2]; unsigned short s[CF]; } pk;
    #pragma unroll
    for (int i = 0; i < CF; ++i) pk.s[i] = f2bf_u16(xv[i]);
    #pragma unroll
    for (int w = 0; w < CF / 2; ++w)
        *(unsigned*)(Xb + (size_t)n * Fin + c0 + w * 2) = pk.u[w];
    float acc[8];
    #pragma unroll
    for (int j = 0; j < 8; ++j) {
        const float* w = wsc + j * 256 + c0;
        float s = 0.f;
        #pragma unroll
        for (int i = 0; i < CF; ++i) s += xv[i] * w[i];
        acc[j] = s;
    }
    #pragma unroll
    for (int o = 32; o; o >>= 1)
        #pragma unroll
        for (int j = 0; j < 8; ++j) acc[j] += __shfl_xor(acc[j], o);
    if (lane == 0) {
        *(float4*)(ssrc + (size_t)n * 4) = make_float4(acc[0], acc[1], acc[2], acc[3]);
        *(float4*)(sdst + (size_t)n * 4) = make_float4(acc[4], acc[5], acc[6], acc[7]);
    }
}

struct CSPair {
    const float* Xf[2]; __hip_bfloat16* Xb[2];
    const float* wsc[2]; float* ssrc[2]; float* sdst[2];
};

__global__ __launch_bounds__(256) void cast_score_pair(CSPair p)
{
    if (blockIdx.y == 0)
        cast_score_body<4>(p.Xf[0], p.Xb[0], p.wsc[0], p.ssrc[0], p.sdst[0]);
    else
        cast_score_body<2>(p.Xf[1], p.Xb[1], p.wsc[1], p.ssrc[1], p.sdst[1]);
}

// ---------------------------------------------------------------- CSR build
__global__ __launch_bounds__(256) void hist_kernel(const int* __restrict__ src, int* __restrict__ cnt)
{
    int i = blockIdx.x * blockDim.x + threadIdx.x;
    if (i < EE) atomicAdd(&cnt[src[i]], 1);
}

__global__ __launch_bounds__(1024) void scan_kernel(const int* __restrict__ cnt, int* __restrict__ row_ptr)
{
    __shared__ int lds[1024];
    int t = threadIdx.x;
    const int CH = 20;
    int start = t * CH, end = start + CH; if (end > NN) end = NN;
    int sum = 0;
    if (start < NN) for (int i = start; i < end; ++i) sum += cnt[i];
    lds[t] = sum;
    __syncthreads();
    for (int o = 1; o < 1024; o <<= 1) {
        int v = (t >= o) ? lds[t - o] : 0;
        __syncthreads();
        lds[t] += v;
        __syncthreads();
    }
    int run = lds[t] - sum;
    if (start < NN) for (int i = start; i < end; ++i) { row_ptr[i] = run; run += cnt[i]; }
    if (t == 1023) row_ptr[NN] = lds[1023];
}

__global__ __launch_bounds__(256) void scatter_kernel(const int* __restrict__ src,
                                                      const int* __restrict__ dst,
                                                      const int* __restrict__ row_ptr,
                                                      int* __restrict__ off,
                                                      int* __restrict__ csr_dst)
{
    int i = blockIdx.x * blockDim.x + threadIdx.x;
    if (i >= EE) return;
    int s = src[i];
    int p = row_ptr[s] + atomicAdd(&off[s], 1);
    csr_dst[p] = dst[i];
}

// ---------------------------------------------------------------- FUSED softmax + aggregate body (float2-packed FMA)
template<int CF>
static __device__ __forceinline__ void agg_body(const __hip_bfloat16* __restrict__ Xb,
                                                const float* __restrict__ ssrc,
                                                const float* __restrict__ sdst,
                                                const int* __restrict__ row_ptr,
                                                const int* __restrict__ csr_dst,
                                                __hip_bfloat16* __restrict__ Cat)
{
    const int Fin = CF * 64, F4 = 4 * Fin;
    const int W2 = CF / 2;                 // dwords (bf16 pairs) per lane
    int wid = threadIdx.x >> 6, lane = threadIdx.x & 63;
    int n = blockIdx.x * 4 + wid;
    if (n >= NN) return;
    int r0 = row_ptr[n], r1 = row_ptr[n + 1];
    int deg = r1 - r0;

    float2 acc[4][W2] = {};
    const __hip_bfloat16* xbase = Xb + lane * CF;

    if (deg > 0) {
        float4 sn = *(const float4*)(ssrc + (size_t)n * 4);
        auto comp_e = [&](int s, int& dout) -> float4 {
            int d = csr_dst[r0 + s];
            dout = d;
            float4 sd = *(const float4*)(sdst + (size_t)d * 4);
            float4 e; float v;
            v = sn.x + sd.x; e.x = v >= 0.f ? v : 0.2f * v;
            v = sn.y + sd.y; e.y = v >= 0.f ? v : 0.2f * v;
            v = sn.z + sd.z; e.z = v >= 0.f ? v : 0.2f * v;
            v = sn.w + sd.w; e.w = v >= 0.f ? v : 0.2f * v;
            return e;
        };

        float4 e0 = make_float4(-1e30f, -1e30f, -1e30f, -1e30f);
        int d0 = 0;
        if (lane < deg) e0 = comp_e(lane, d0);
        float4 m = e0;
        for (int s = lane + 64; s < deg; s += 64) {
            int dt; float4 ev = comp_e(s, dt);
            m.x = fmaxf(m.x, ev.x); m.y = fmaxf(m.y, ev.y);
            m.z = fmaxf(m.z, ev.z); m.w = fmaxf(m.w, ev.w);
        }
        #pragma unroll
        for (int o = 32; o; o >>= 1) {
            m.x = fmaxf(m.x, __shfl_xor(m.x, o));
            m.y = fmaxf(m.y, __shfl_xor(m.y, o));
            m.z = fmaxf(m.z, __shfl_xor(m.z, o));
            m.w = fmaxf(m.w, __shfl_xor(m.w, o));
        }
        float4 p0 = make_float4(0.f, 0.f, 0.f, 0.f);
        if (lane < deg) {
            p0.x = expf(e0.x - m.x); p0.y = expf(e0.y - m.y);
            p0.z = expf(e0.z - m.z); p0.w = expf(e0.w - m.w);
        }
        float4 den = p0;
        for (int s = lane + 64; s < deg; s += 64) {
            int dt; float4 ev = comp_e(s, dt);
            den.x += expf(ev.x - m.x); den.y += expf(ev.y - m.y);
            den.z += expf(ev.z - m.z); den.w += expf(ev.w - m.w);
        }
        #pragma unroll
        for (int o = 32; o; o >>= 1) {
            den.x += __shfl_xor(den.x, o); den.y += __shfl_xor(den.y, o);
            den.z += __shfl_xor(den.z, o); den.w += __shfl_xor(den.w, o);
        }
        den.x = 1.f / (den.x + 1e-16f); den.y = 1.f / (den.y + 1e-16f);
        den.z = 1.f / (den.z + 1e-16f); den.w = 1.f / (den.w + 1e-16f);

        float4 a0;
        a0.x = p0.x * den.x; a0.y = p0.y * den.y;
        a0.z = p0.z * den.z; a0.w = p0.w * den.w;

        // packed-FMA accumulate of one edge
        auto fma_edge = [&](const unsigned (&u)[W2], float ax, float ay, float az, float aw) {
            #pragma unroll
            for (int w = 0; w < W2; ++w) {
                float2 xv = bfpair(u[w]);
                acc[0][w].x += ax * xv.x; acc[0][w].y += ax * xv.y;
                acc[1][w].x += ay * xv.x; acc[1][w].y += ay * xv.y;
                acc[2][w].x += az * xv.x; acc[2][w].y += az * xv.y;
                acc[3][w].x += aw * xv.x; acc[3][w].y += aw * xv.y;
            }
        };

        int cnt0 = min(deg, 64);
        int last = cnt0 - 1;
        for (int base = 0; base < cnt0; base += 4) {
            int j1 = min(base + 1, last), j2 = min(base + 2, last), j3 = min(base + 3, last);
            int dv0 = __shfl(d0, base), dv1 = __shfl(d0, j1);
            int dv2 = __shfl(d0, j2),   dv3 = __shfl(d0, j3);
            unsigned l0[W2], l1[W2], l2[W2], l3[W2];
            #pragma unroll
            for (int w = 0; w < W2; ++w)
                l0[w] = *(const unsigned*)(xbase + (size_t)dv0 * Fin + w * 2);
            #pragma unroll
            for (int w = 0; w < W2; ++w)
                l1[w] = *(const unsigned*)(xbase + (size_t)dv1 * Fin + w * 2);
            #pragma unroll
            for (int w = 0; w < W2; ++w)
                l2[w] = *(const unsigned*)(xbase + (size_t)dv2 * Fin + w * 2);
            #pragma unroll
            for (int w = 0; w < W2; ++w)
                l3[w] = *(const unsigned*)(xbase + (size_t)dv3 * Fin + w * 2);

            fma_edge(l0, __shfl(a0.x, base), __shfl(a0.y, base), __shfl(a0.z, base), __shfl(a0.w, base));
            if (base + 1 < cnt0)
                fma_edge(l1, __shfl(a0.x, j1), __shfl(a0.y, j1), __shfl(a0.z, j1), __shfl(a0.w, j1));
            if (base + 2 < cnt0)
                fma_edge(l2, __shfl(a0.x, j2), __shfl(a0.y, j2), __shfl(a0.z, j2), __shfl(a0.w, j2));
            if (base + 3 < cnt0)
                fma_edge(l3, __shfl(a0.x, j3), __shfl(a0.y, j3), __shfl(a0.z, j3), __shfl(a0.w, j3));
        }

        // cold chunks (deg > 64): recompute alpha then broadcast
        for (int r = r0 + 64; r < r1; r += 64) {
            int cnt = min(64, r1 - r);
            int d = 0;
            float4 a4 = make_float4(0.f, 0.f, 0.f, 0.f);
            if (r + lane < r1) {
                int dt;
                float4 ev = comp_e(r - r0 + lane, dt);
                d = dt;
                a4.x = expf(ev.x - m.x) * den.x; a4.y = expf(ev.y - m.y) * den.y;
                a4.z = expf(ev.z - m.z) * den.z; a4.w = expf(ev.w - m.w) * den.w;
            }
            for (int j = 0; j < cnt; ++j) {
                int ddv = __shfl(d, j);
                unsigned lu[W2];
                #pragma unroll
                for (int w = 0; w < W2; ++w)
                    lu[w] = *(const unsigned*)(xbase + (size_t)ddv * Fin + w * 2);
                fma_edge(lu, __shfl(a4.x, j), __shfl(a4.y, j), __shfl(a4.z, j), __shfl(a4.w, j));
            }
        }
    }

    __hip_bfloat16* crow = Cat + (size_t)n * F4;
    #pragma unroll
    for (int h = 0; h < 4; ++h) {
        union { unsigned u[W2]; unsigned short s[CF]; } pk;
        #pragma unroll
        for (int w = 0; w < W2; ++w) {
            pk.s[w * 2 + 0] = f2bf_u16(acc[h][w].x);
            pk.s[w * 2 + 1] = f2bf_u16(acc[h][w].y);
        }
        #pragma unroll
        for (int w = 0; w < W2; ++w)
            *(unsigned*)(crow + h * Fin + lane * CF + w * 2) = pk.u[w];
    }
}

struct AggPair {
    const __hip_bfloat16* Xb[2];
    const float* ssrc[2]; const float* sdst[2];
    __hip_bfloat16* Cat[2];
};

template<int CF0, int CF1>
__global__ __launch_bounds__(256) void agg_pair_kernel(AggPair p,
                                                       const int* __restrict__ row_ptr,
                                                       const int* __restrict__ csr_dst)
{
    if (blockIdx.y == 0)
        agg_body<CF0>(p.Xb[0], p.ssrc[0], p.sdst[0], row_ptr, csr_dst, p.Cat[0]);
    else
        agg_body<CF1>(p.Xb[1], p.ssrc[1], p.sdst[1], row_ptr, csr_dst, p.Cat[1]);
}

// ---------------------------------------------------------------- MFMA GEMM + ELU + SE-pool + optional next scores (bf16-only output)
struct GemmArgs {
    const __hip_bfloat16 *Cat, *Xb, *Wct;
    __hip_bfloat16* xbout;
    const float* wscN; float *ssrcN, *sdstN;
    int F4, FIN, ch;
};
struct GemmPair { GemmArgs g[2]; };

__global__ __launch_bounds__(256) void gemm_pair_kernel(GemmPair p, float* __restrict__ sums)
{
    GemmArgs a = (blockIdx.y == 0) ? p.g[0] : p.g[1];
    const int F4 = a.F4, FIN = a.FIN;
    const int KK = F4 + FIN;
    const int BK = 64;
    const int NIT = KK / BK;
    __shared__ short As[2][32 * 72];
    __shared__ short Bs[2][128 * 72];
    __shared__ float ls[4];
    __shared__ float sred[4][4][4][8];

    int tid = threadIdx.x, lane = tid & 63, wid = tid >> 6;
    int wr = wid >> 1, wc = wid & 1;
    int ar = lane & 15, kg = lane >> 4;
    int row0 = blockIdx.x * 32;

    int a_row = tid >> 3, a_seg = tid & 7;
    int b_col = tid >> 1, b_seg0 = (tid & 1) * 4;

    const __hip_bfloat16* AgC = a.Cat + (size_t)(row0 + a_row) * F4 + a_seg * 8;
    const __hip_bfloat16* AgX = a.Xb + (size_t)(row0 + a_row) * FIN + a_seg * 8;
    const __hip_bfloat16* Bg = a.Wct + (size_t)b_col * KK + b_seg0 * 8;

    short8v fa, fb0, fb1, fb2, fb3;
    f32x4 acc[4] = {};

    fa  = *(const short8v*)(AgC);
    fb0 = *(const short8v*)(Bg);
    fb1 = *(const short8v*)(Bg + 8);
    fb2 = *(const short8v*)(Bg + 16);
    fb3 = *(const short8v*)(Bg + 24);
    *(short8v*)(&As[0][a_row * 72 + a_seg * 8]) = fa;
    *(short8v*)(&Bs[0][b_col * 72 + (b_seg0 + 0) * 8]) = fb0;
    *(short8v*)(&Bs[0][b_col * 72 + (b_seg0 + 1) * 8]) = fb1;
    *(short8v*)(&Bs[0][b_col * 72 + (b_seg0 + 2) * 8]) = fb2;
    *(short8v*)(&Bs[0][b_col * 72 + (b_seg0 + 3) * 8]) = fb3;

    int cur = 0;
    for (int it = 0; it < NIT; ++it) {
        if (it + 1 < NIT) {
            int kb = (it + 1) * BK;
            fa  = (kb < F4) ? *(const short8v*)(AgC + kb) : *(const short8v*)(AgX + (kb - F4));
            fb0 = *(const short8v*)(Bg + kb);
            fb1 = *(const short8v*)(Bg + kb + 8);
            fb2 = *(const short8v*)(Bg + kb + 16);
            fb3 = *(const short8v*)(Bg + kb + 24);
        }
        __syncthreads();
        #pragma unroll
        for (int ks = 0; ks < 2; ++ks) {
            short8v av = *(const short8v*)(&As[cur][(wr * 16 + ar) * 72 + ks * 32 + kg * 8]);
            #pragma unroll
            for (int nb = 0; nb < 4; ++nb) {
                short8v bv = *(const short8v*)(&Bs[cur][(wc * 64 + nb * 16 + ar) * 72 + ks * 32 + kg * 8]);
                acc[nb] = __builtin_amdgcn_mfma_f32_16x16x32_bf16(av, bv, acc[nb], 0, 0, 0);
            }
        }
        if (it + 1 < NIT) {
            int nb2 = cur ^ 1;
            *(short8v*)(&As[nb2][a_row * 72 + a_seg * 8]) = fa;
            *(short8v*)(&Bs[nb2][b_col * 72 + (b_seg0 + 0) * 8]) = fb0;
            *(short8v*)(&Bs[nb2][b_col * 72 + (b_seg0 + 1) * 8]) = fb1;
            *(short8v*)(&Bs[nb2][b_col * 72 + (b_seg0 + 2) * 8]) = fb2;
            *(short8v*)(&Bs[nb2][b_col * 72 + (b_seg0 + 3) * 8]) = fb3;
        }
        cur ^= 1;
    }

    float lsum = 0.f;
    float vpost[4][4];
    int rsub = (lane >> 4) * 4;
    #pragma unroll
    for (int nb = 0; nb < 4; ++nb) {
        int col = wc * 64 + nb * 16 + ar;
        #pragma unroll
        for (int r = 0; r < 4; ++r) {
            int row = row0 + wr * 16 + rsub + r;
            float v = acc[nb][r];
            v = v > 0.f ? v : expm1f(v);
            vpost[nb][r] = v;
            lsum += v;
            a.xbout[(size_t)row * 128 + col] = __float2bfloat16(v);
        }
    }
    #pragma unroll
    for (int o = 32; o; o >>= 1) lsum += __shfl_xor(lsum, o);
    if (lane == 0) ls[wid] = lsum;

    bool dosc = a.wscN != nullptr;
    if (dosc) {
        float sc[4][8] = {};
        #pragma unroll
        for (int j = 0; j < 8; ++j) {
            #pragma unroll
            for (int nb = 0; nb < 4; ++nb) {
                float wv = a.wscN[j * 256 + wc * 64 + nb * 16 + ar];
                #pragma unroll
                for (int r = 0; r < 4; ++r) sc[r][j] += vpost[nb][r] * wv;
            }
        }
        #pragma unroll
        for (int o = 8; o; o >>= 1)
            #pragma unroll
            for (int r = 0; r < 4; ++r)
                #pragma unroll
                for (int j = 0; j < 8; ++j) sc[r][j] += __shfl_xor(sc[r][j], o);
        if (ar == 0) {
            int grp = lane >> 4;
            #pragma unroll
            for (int r = 0; r < 4; ++r)
                #pragma unroll
                for (int j = 0; j < 8; ++j) sred[wid][grp][r][j] = sc[r][j];
        }
    }
    __syncthreads();
    if (tid == 0) atomicAdd(&sums[a.ch], ls[0] + ls[1] + ls[2] + ls[3]);
    if (dosc) {
        int row_local = tid >> 3, j = tid & 7;
        int w_r = row_local >> 4, grp = (row_local >> 2) & 3, r = row_local & 3;
        float total = sred[w_r * 2 + 0][grp][r][j] + sred[w_r * 2 + 1][grp][r][j];
        int row = row0 + row_local;
        if (j < 4) a.ssrcN[(size_t)row * 4 + j] = total;
        else       a.sdstN[(size_t)row * 4 + (j - 4)] = total;
    }
}

// ---------------------------------------------------------------- final: inline SE MLP + relu(att*x) conv, bf16 inputs
__global__ __launch_bounds__(256) void final_kernel(const __hip_bfloat16* __restrict__ x1,
                                                    const __hip_bfloat16* __restrict__ x2,
                                                    const __hip_bfloat16* __restrict__ d1,
                                                    const __hip_bfloat16* __restrict__ d2,
                                                    const float* __restrict__ sums,
                                                    const float* __restrict__ fc1w, const float* __restrict__ fc1b,
                                                    const float* __restrict__ fc2w, const float* __restrict__ fc2b,
                                                    const float* __restrict__ convw,
                                                    const float* __restrict__ convb,
                                                    float* __restrict__ out)
{
    float att[4];
    {
        float avg[4];
        #pragma unroll
        for (int c = 0; c < 4; ++c) avg[c] = sums[c] * (1.f / (NN * 128.f));
        float z[20];
        #pragma unroll
        for (int j = 0; j < 20; ++j) {
            float v = fc1b[j];
            #pragma unroll
            for (int c = 0; c < 4; ++c) v += avg[c] * fc1w[c * 20 + j];
            z[j] = v;
        }
        #pragma unroll
        for (int c = 0; c < 4; ++c) {
            float v = fc2b[c];
            #pragma unroll
            for (int j = 0; j < 20; ++j) v += z[j] * fc2w[j * 4 + c];
            att[c] = 1.f / (1.f + expf(-v));
        }
    }
    int i = (blockIdx.x * 256 + threadIdx.x) * 2;
    if (i >= NN * 128) return;
    unsigned u1 = *(const unsigned*)(x1 + i);
    unsigned u2 = *(const unsigned*)(x2 + i);
    unsigned u3 = *(const unsigned*)(d1 + i);
    unsigned u4 = *(const unsigned*)(d2 + i);
    float w0 = convw[0], w1 = convw[1], w2 = convw[2], w3 = convw[3];
    float cb = convb[0];
    float2 v1 = bfpair(u1), v2 = bfpair(u2), v3 = bfpair(u3), v4 = bfpair(u4);
    float2 r;
    r.x = cb + w0 * fmaxf(att[0] * v1.x, 0.f) + w1 * fmaxf(att[1] * v2.x, 0.f)
             + w2 * fmaxf(att[2] * v3.x, 0.f) + w3 * fmaxf(att[3] * v4.x, 0.f);
    r.y = cb + w0 * fmaxf(att[0] * v1.y, 0.f) + w1 * fmaxf(att[1] * v2.y, 0.f)
             + w2 * fmaxf(att[2] * v3.y, 0.f) + w3 * fmaxf(att[3] * v4.y, 0.f);
    *(float2*)(out + i) = r;
}

// ---------------------------------------------------------------- host
extern "C" void kernel_launch(void* const* d_in, const int* in_sizes, int n_in,
                              void* d_out, int out_size, void* d_ws, size_t ws_size,
                              hipStream_t stream)
{
    (void)in_sizes; (void)n_in; (void)out_size; (void)ws_size;
    const float* x    = (const float*)d_in[0];
    const float* dat  = (const float*)d_in[1];
    const float* W1   = (const float*)d_in[2];
    const float* a1s  = (const float*)d_in[3];
    const float* a1d  = (const float*)d_in[4];
    const float* R1   = (const float*)d_in[5];
    const float* W2   = (const float*)d_in[6];
    const float* a2s  = (const float*)d_in[7];
    const float* a2d  = (const float*)d_in[8];
    const float* R2   = (const float*)d_in[9];
    const float* Wd1  = (const float*)d_in[10];
    const float* ad1s = (const float*)d_in[11];
    const float* ad1d = (const float*)d_in[12];
    const float* Rd1  = (const float*)d_in[13];
    const float* Wd2  = (const float*)d_in[14];
    const float* ad2s = (const float*)d_in[15];
    const float* ad2d = (const float*)d_in[16];
    const float* Rd2  = (const float*)d_in[17];
    const float* fc1w = (const float*)d_in[18];
    const float* fc1b = (const float*)d_in[19];
    const float* fc2w = (const float*)d_in[20];
    const float* fc2b = (const float*)d_in[21];
    const float* convw= (const float*)d_in[22];
    const float* convb= (const float*)d_in[23];
    const int*   eidx = (const int*)d_in[24];
    const int* esrc = eidx;
    const int* edst = eidx + EE;
    float* out = (float*)d_out;

    char* base = (char*)d_ws;
    size_t woff = 0;
    auto alloc = [&](size_t bytes) -> void* {
        void* p = base + woff;
        woff = (woff + bytes + 255) & ~(size_t)255;
        return p;
    };
    __hip_bfloat16* Cat0 = (__hip_bfloat16*)alloc((size_t)NN * 1024 * 2);
    __hip_bfloat16* Cat2 = (__hip_bfloat16*)alloc((size_t)NN * 512 * 2);
    __hip_bfloat16* XbX   = (__hip_bfloat16*)alloc((size_t)NN * FXX * 2);
    __hip_bfloat16* XbDat = (__hip_bfloat16*)alloc((size_t)NN * FWW * 2);
    __hip_bfloat16* Xb1   = (__hip_bfloat16*)alloc((size_t)NN * 128 * 2);
    __hip_bfloat16* XbD1  = (__hip_bfloat16*)alloc((size_t)NN * 128 * 2);
    __hip_bfloat16* Xb2   = (__hip_bfloat16*)alloc((size_t)NN * 128 * 2);
    __hip_bfloat16* XbD2  = (__hip_bfloat16*)alloc((size_t)NN * 128 * 2);
    float* Wsc   = (float*)alloc((size_t)4 * 2048 * 4);
    __hip_bfloat16* Wct0 = (__hip_bfloat16*)alloc((size_t)128 * 1280 * 2);
    __hip_bfloat16* Wct1 = (__hip_bfloat16*)alloc((size_t)128 * 640 * 2);
    __hip_bfloat16* Wct2 = (__hip_bfloat16*)alloc((size_t)128 * 640 * 2);
    __hip_bfloat16* Wct3 = (__hip_bfloat16*)alloc((size_t)128 * 640 * 2);
    float* SsrcX = (float*)alloc((size_t)NN * 4 * 4);
    float* SdstX = (float*)alloc((size_t)NN * 4 * 4);
    float* Ssrc1 = (float*)alloc((size_t)NN * 4 * 4);
    float* Sdst1 = (float*)alloc((size_t)NN * 4 * 4);
    float* SsrcD = (float*)alloc((size_t)NN * 4 * 4);
    float* SdstD = (float*)alloc((size_t)NN * 4 * 4);
    float* Ssrc3 = (float*)alloc((size_t)NN * 4 * 4);
    float* Sdst3 = (float*)alloc((size_t)NN * 4 * 4);
    int* RowPtr  = (int*)alloc((size_t)(NN + 1) * 4);
    int* Cnt     = (int*)alloc((size_t)NN * 4);
    int* Off     = (int*)alloc((size_t)NN * 4);
    int* CsrDst  = (int*)alloc((size_t)EE * 4);
    float* Sums  = (float*)alloc(16);

    // setup
    {
        WscParams WP;
        WP.t[0] = { W1,  a1s,  a1d,  FXX };
        WP.t[1] = { W2,  a2s,  a2d,  FWW };
        WP.t[2] = { Wd1, ad1s, ad1d, FWW };
        WP.t[3] = { Wd2, ad2s, ad2d, FWW };
        wsc_kernel<<<dim3(256, 1, 4), 256, 0, stream>>>(WP, Wsc);
        WcParams CP;
        CP.t[0] = { W1,  R1,  Wct0, FXX, 1280, 128 * 1280 };
        CP.t[1] = { W2,  R2,  Wct1, FWW, 640,  128 * 640 };
        CP.t[2] = { Wd1, Rd1, Wct2, FWW, 640,  128 * 640 };
        CP.t[3] = { Wd2, Rd2, Wct3, FWW, 640,  128 * 640 };
        wcomb_kernel<<<dim3(640, 1, 4), 256, 0, stream>>>(CP);
        CSPair CS;
        CS.Xf[0] = x;   CS.Xb[0] = XbX;   CS.wsc[0] = Wsc;            CS.ssrc[0] = SsrcX; CS.sdst[0] = SdstX;
        CS.Xf[1] = dat; CS.Xb[1] = XbDat; CS.wsc[1] = Wsc + 2 * 2048; CS.ssrc[1] = SsrcD; CS.sdst[1] = SdstD;
        cast_score_pair<<<dim3((NN + 3) / 4, 2), 256, 0, stream>>>(CS);
    }
    hipMemsetAsync(Cnt, 0, (size_t)NN * 4, stream);
    hipMemsetAsync(Off, 0, (size_t)NN * 4, stream);
    hipMemsetAsync(Sums, 0, 16, stream);
    hist_kernel<<<(EE + 255) / 256, 256, 0, stream>>>(esrc, Cnt);
    scan_kernel<<<1, 1024, 0, stream>>>(Cnt, RowPtr);
    scatter_kernel<<<(EE + 255) / 256, 256, 0, stream>>>(esrc, edst, RowPtr, Off, CsrDst);

    // stage A: agg layers {0, 2}
    {
        AggPair AP;
        AP.Xb[0] = XbX;   AP.ssrc[0] = SsrcX; AP.sdst[0] = SdstX; AP.Cat[0] = Cat0;
        AP.Xb[1] = XbDat; AP.ssrc[1] = SsrcD; AP.sdst[1] = SdstD; AP.Cat[1] = Cat2;
        agg_pair_kernel<4, 2><<<dim3((NN + 3) / 4, 2), 256, 0, stream>>>(AP, RowPtr, CsrDst);
    }
    // stage B: gemm layers {0, 2} (+ next-layer scores)
    {
        GemmPair GP;
        GP.g[0] = { Cat0, XbX,   Wct0, Xb1,  Wsc + 1 * 2048, Ssrc1, Sdst1, 1024, 256, 0 };
        GP.g[1] = { Cat2, XbDat, Wct2, XbD1, Wsc + 3 * 2048, Ssrc3, Sdst3, 512,  128, 2 };
        gemm_pair_kernel<<<dim3(NN / 32, 2), 256, 0, stream>>>(GP, Sums);
    }
    // stage C: agg layers {1, 3}
    {
        AggPair AP;
        AP.Xb[0] = Xb1;  AP.ssrc[0] = Ssrc1; AP.sdst[0] = Sdst1; AP.Cat[0] = Cat0;
        AP.Xb[1] = XbD1; AP.ssrc[1] = Ssrc3; AP.sdst[1] = Sdst3; AP.Cat[1] = Cat2;
        agg_pair_kernel<2, 2><<<dim3((NN + 3) / 4, 2), 256, 0, stream>>>(AP, RowPtr, CsrDst);
    }
    // stage D: gemm layers {1, 3}
    {
        GemmPair GP;
        GP.g[0] = { Cat0, Xb1,  Wct1, Xb2,  nullptr, nullptr, nullptr, 512, 128, 1 };
        GP.g[1] = { Cat2, XbD1, Wct3, XbD2, nullptr, nullptr, nullptr, 512, 128, 3 };
        gemm_pair_kernel<<<dim3(NN / 32, 2), 256, 0, stream>>>(GP, Sums);
    }

    final_kernel<<<(NN * 128 / 2 + 255) / 256, 256, 0, stream>>>(Xb1, Xb2, XbD1, XbD2, Sums,
                                                                 fc1w, fc1b, fc2w, fc2b,
                                                                 convw, convb, out);
}

// Round 17
// 300.506 us; speedup vs baseline: 1.0725x; 1.0690x over previous
//
#include <hip/hip_runtime.h>
#include <hip/hip_bf16.h>
#include <math.h>

#define NN 20000
#define EE 320000
#define FXX 256
#define FWW 128
#define NH 4

typedef __attribute__((ext_vector_type(8))) short short8v;
typedef __attribute__((ext_vector_type(4))) float f32x4;

static __device__ __forceinline__ float bf2f(unsigned short s) {
    unsigned int u = ((unsigned int)s) << 16;
    return __builtin_bit_cast(float, u);
}

static __device__ __forceinline__ unsigned short f2bf_u16(float f) {
    unsigned int u = __builtin_bit_cast(unsigned int, f);
    unsigned int r = 0x7fffu + ((u >> 16) & 1u);
    return (unsigned short)((u + r) >> 16);
}

// unpack one dword of 2 bf16 into 2 exact floats (2 VALU ops)
static __device__ __forceinline__ float2 bfpair(unsigned u) {
    float lo = __builtin_bit_cast(float, u << 16);
    float hi = __builtin_bit_cast(float, u & 0xFFFF0000u);
    return make_float2(lo, hi);
}

// ---------------------------------------------------------------- w~ = W_h @ a (score projection vectors), fp32
struct WscItem { const float* W; const float* as_; const float* ad_; int Fin; };
struct WscParams { WscItem t[4]; };

__global__ __launch_bounds__(256) void wsc_kernel(WscParams p, float* __restrict__ wsc)
{
    int L = blockIdx.z;
    WscItem it = p.t[L];
    int wid = threadIdx.x >> 6, lane = threadIdx.x & 63;
    int r = blockIdx.x * 4 + wid;
    if (r >= it.Fin * 4) return;
    int h = r / it.Fin, k = r - h * it.Fin;
    float2 w2 = *(const float2*)(it.W + ((size_t)(h * it.Fin + k)) * 128 + 2 * lane);
    float2 s2 = *(const float2*)(it.as_ + h * 128 + 2 * lane);
    float2 d2 = *(const float2*)(it.ad_ + h * 128 + 2 * lane);
    float vs = w2.x * s2.x + w2.y * s2.y;
    float vd = w2.x * d2.x + w2.y * d2.y;
    #pragma unroll
    for (int o = 32; o; o >>= 1) { vs += __shfl_xor(vs, o); vd += __shfl_xor(vd, o); }
    if (lane == 0) {
        wsc[(size_t)L * 2048 + h * 256 + k] = vs;
        wsc[(size_t)L * 2048 + (4 + h) * 256 + k] = vd;
    }
}

// ---------------------------------------------------------------- combined GEMM weights
struct WcItem { const float* W; const float* R; __hip_bfloat16* dst; int Fin; int KK; int total; };
struct WcParams { WcItem t[4]; };

__global__ __launch_bounds__(256) void wcomb_kernel(WcParams p)
{
    WcItem it = p.t[blockIdx.z];
    int idx = blockIdx.x * 256 + threadIdx.x;
    if (idx >= it.total) return;
    int c = idx / it.KK;
    int k5 = idx - c * it.KK;
    int f4 = it.Fin * 4;
    float v;
    if (k5 < f4) {
        int h = k5 / it.Fin, k = k5 - h * it.Fin;
        v = 0.25f * it.W[((size_t)(h * it.Fin + k)) * 128 + c];
    } else {
        v = it.R[(size_t)(k5 - f4) * 128 + c];
    }
    it.dst[(size_t)c * it.KK + k5] = __float2bfloat16(v);
}

// ---------------------------------------------------------------- fused cast + scores (both inputs, one dispatch)
template<int CF>
static __device__ __forceinline__ void cast_score_body(const float* __restrict__ Xf,
                                                       __hip_bfloat16* __restrict__ Xb,
                                                       const float* __restrict__ wsc,
                                                       float* __restrict__ ssrc,
                                                       float* __restrict__ sdst)
{
    const int Fin = CF * 64;
    int wid = threadIdx.x >> 6, lane = threadIdx.x & 63;
    int n = blockIdx.x * 4 + wid;
    if (n >= NN) return;
    int c0 = lane * CF;
    float xv[CF];
    #pragma unroll
    for (int i = 0; i < CF; ++i) xv[i] = Xf[(size_t)n * Fin + c0 + i];
    union { unsigned u[CF / 2]; unsigned short s[CF]; } pk;
    #pragma unroll
    for (int i = 0; i < CF; ++i) pk.s[i] = f2bf_u16(xv[i]);
    #pragma unroll
    for (int w = 0; w < CF / 2; ++w)
        *(unsigned*)(Xb + (size_t)n * Fin + c0 + w * 2) = pk.u[w];
    float acc[8];
    #pragma unroll
    for (int j = 0; j < 8; ++j) {
        const float* w = wsc + j * 256 + c0;
        float s = 0.f;
        #pragma unroll
        for (int i = 0; i < CF; ++i) s += xv[i] * w[i];
        acc[j] = s;
    }
    #pragma unroll
    for (int o = 32; o; o >>= 1)
        #pragma unroll
        for (int j = 0; j < 8; ++j) acc[j] += __shfl_xor(acc[j], o);
    if (lane == 0) {
        *(float4*)(ssrc + (size_t)n * 4) = make_float4(acc[0], acc[1], acc[2], acc[3]);
        *(float4*)(sdst + (size_t)n * 4) = make_float4(acc[4], acc[5], acc[6], acc[7]);
    }
}

struct CSPair {
    const float* Xf[2]; __hip_bfloat16* Xb[2];
    const float* wsc[2]; float* ssrc[2]; float* sdst[2];
};

__global__ __launch_bounds__(256) void cast_score_pair(CSPair p)
{
    if (blockIdx.y == 0)
        cast_score_body<4>(p.Xf[0], p.Xb[0], p.wsc[0], p.ssrc[0], p.sdst[0]);
    else
        cast_score_body<2>(p.Xf[1], p.Xb[1], p.wsc[1], p.ssrc[1], p.sdst[1]);
}

// ---------------------------------------------------------------- CSR build
__global__ __launch_bounds__(256) void hist_kernel(const int* __restrict__ src, int* __restrict__ cnt)
{
    int i = blockIdx.x * blockDim.x + threadIdx.x;
    if (i < EE) atomicAdd(&cnt[src[i]], 1);
}

__global__ __launch_bounds__(1024) void scan_kernel(const int* __restrict__ cnt, int* __restrict__ row_ptr)
{
    __shared__ int lds[1024];
    int t = threadIdx.x;
    const int CH = 20;
    int start = t * CH, end = start + CH; if (end > NN) end = NN;
    int sum = 0;
    if (start < NN) for (int i = start; i < end; ++i) sum += cnt[i];
    lds[t] = sum;
    __syncthreads();
    for (int o = 1; o < 1024; o <<= 1) {
        int v = (t >= o) ? lds[t - o] : 0;
        __syncthreads();
        lds[t] += v;
        __syncthreads();
    }
    int run = lds[t] - sum;
    if (start < NN) for (int i = start; i < end; ++i) { row_ptr[i] = run; run += cnt[i]; }
    if (t == 1023) row_ptr[NN] = lds[1023];
}

__global__ __launch_bounds__(256) void scatter_kernel(const int* __restrict__ src,
                                                      const int* __restrict__ dst,
                                                      const int* __restrict__ row_ptr,
                                                      int* __restrict__ off,
                                                      int* __restrict__ csr_dst)
{
    int i = blockIdx.x * blockDim.x + threadIdx.x;
    if (i >= EE) return;
    int s = src[i];
    int p = row_ptr[s] + atomicAdd(&off[s], 1);
    csr_dst[p] = dst[i];
}

// ---------------------------------------------------------------- FUSED softmax + aggregate body (float2-packed FMA)
template<int CF>
static __device__ __forceinline__ void agg_body(const __hip_bfloat16* __restrict__ Xb,
                                                const float* __restrict__ ssrc,
                                                const float* __restrict__ sdst,
                                                const int* __restrict__ row_ptr,
                                                const int* __restrict__ csr_dst,
                                                __hip_bfloat16* __restrict__ Cat)
{
    const int Fin = CF * 64, F4 = 4 * Fin;
    const int W2 = CF / 2;                 // dwords (bf16 pairs) per lane
    int wid = threadIdx.x >> 6, lane = threadIdx.x & 63;
    int n = blockIdx.x * 4 + wid;
    if (n >= NN) return;
    int r0 = row_ptr[n], r1 = row_ptr[n + 1];
    int deg = r1 - r0;

    float2 acc[4][W2] = {};
    const __hip_bfloat16* xbase = Xb + lane * CF;

    if (deg > 0) {
        float4 sn = *(const float4*)(ssrc + (size_t)n * 4);
        auto comp_e = [&](int s, int& dout) -> float4 {
            int d = csr_dst[r0 + s];
            dout = d;
            float4 sd = *(const float4*)(sdst + (size_t)d * 4);
            float4 e; float v;
            v = sn.x + sd.x; e.x = v >= 0.f ? v : 0.2f * v;
            v = sn.y + sd.y; e.y = v >= 0.f ? v : 0.2f * v;
            v = sn.z + sd.z; e.z = v >= 0.f ? v : 0.2f * v;
            v = sn.w + sd.w; e.w = v >= 0.f ? v : 0.2f * v;
            return e;
        };

        float4 e0 = make_float4(-1e30f, -1e30f, -1e30f, -1e30f);
        int d0 = 0;
        if (lane < deg) e0 = comp_e(lane, d0);
        float4 m = e0;
        for (int s = lane + 64; s < deg; s += 64) {
            int dt; float4 ev = comp_e(s, dt);
            m.x = fmaxf(m.x, ev.x); m.y = fmaxf(m.y, ev.y);
            m.z = fmaxf(m.z, ev.z); m.w = fmaxf(m.w, ev.w);
        }
        #pragma unroll
        for (int o = 32; o; o >>= 1) {
            m.x = fmaxf(m.x, __shfl_xor(m.x, o));
            m.y = fmaxf(m.y, __shfl_xor(m.y, o));
            m.z = fmaxf(m.z, __shfl_xor(m.z, o));
            m.w = fmaxf(m.w, __shfl_xor(m.w, o));
        }
        float4 p0 = make_float4(0.f, 0.f, 0.f, 0.f);
        if (lane < deg) {
            p0.x = expf(e0.x - m.x); p0.y = expf(e0.y - m.y);
            p0.z = expf(e0.z - m.z); p0.w = expf(e0.w - m.w);
        }
        float4 den = p0;
        for (int s = lane + 64; s < deg; s += 64) {
            int dt; float4 ev = comp_e(s, dt);
            den.x += expf(ev.x - m.x); den.y += expf(ev.y - m.y);
            den.z += expf(ev.z - m.z); den.w += expf(ev.w - m.w);
        }
        #pragma unroll
        for (int o = 32; o; o >>= 1) {
            den.x += __shfl_xor(den.x, o); den.y += __shfl_xor(den.y, o);
            den.z += __shfl_xor(den.z, o); den.w += __shfl_xor(den.w, o);
        }
        den.x = 1.f / (den.x + 1e-16f); den.y = 1.f / (den.y + 1e-16f);
        den.z = 1.f / (den.z + 1e-16f); den.w = 1.f / (den.w + 1e-16f);

        float4 a0;
        a0.x = p0.x * den.x; a0.y = p0.y * den.y;
        a0.z = p0.z * den.z; a0.w = p0.w * den.w;

        auto fma_edge = [&](const unsigned (&u)[W2], float ax, float ay, float az, float aw) {
            #pragma unroll
            for (int w = 0; w < W2; ++w) {
                float2 xv = bfpair(u[w]);
                acc[0][w].x += ax * xv.x; acc[0][w].y += ax * xv.y;
                acc[1][w].x += ay * xv.x; acc[1][w].y += ay * xv.y;
                acc[2][w].x += az * xv.x; acc[2][w].y += az * xv.y;
                acc[3][w].x += aw * xv.x; acc[3][w].y += aw * xv.y;
            }
        };

        int cnt0 = min(deg, 64);
        int last = cnt0 - 1;
        for (int base = 0; base < cnt0; base += 4) {
            int j1 = min(base + 1, last), j2 = min(base + 2, last), j3 = min(base + 3, last);
            int dv0 = __shfl(d0, base), dv1 = __shfl(d0, j1);
            int dv2 = __shfl(d0, j2),   dv3 = __shfl(d0, j3);
            unsigned l0[W2], l1[W2], l2[W2], l3[W2];
            #pragma unroll
            for (int w = 0; w < W2; ++w)
                l0[w] = *(const unsigned*)(xbase + (size_t)dv0 * Fin + w * 2);
            #pragma unroll
            for (int w = 0; w < W2; ++w)
                l1[w] = *(const unsigned*)(xbase + (size_t)dv1 * Fin + w * 2);
            #pragma unroll
            for (int w = 0; w < W2; ++w)
                l2[w] = *(const unsigned*)(xbase + (size_t)dv2 * Fin + w * 2);
            #pragma unroll
            for (int w = 0; w < W2; ++w)
                l3[w] = *(const unsigned*)(xbase + (size_t)dv3 * Fin + w * 2);

            fma_edge(l0, __shfl(a0.x, base), __shfl(a0.y, base), __shfl(a0.z, base), __shfl(a0.w, base));
            if (base + 1 < cnt0)
                fma_edge(l1, __shfl(a0.x, j1), __shfl(a0.y, j1), __shfl(a0.z, j1), __shfl(a0.w, j1));
            if (base + 2 < cnt0)
                fma_edge(l2, __shfl(a0.x, j2), __shfl(a0.y, j2), __shfl(a0.z, j2), __shfl(a0.w, j2));
            if (base + 3 < cnt0)
                fma_edge(l3, __shfl(a0.x, j3), __shfl(a0.y, j3), __shfl(a0.z, j3), __shfl(a0.w, j3));
        }

        for (int r = r0 + 64; r < r1; r += 64) {
            int cnt = min(64, r1 - r);
            int d = 0;
            float4 a4 = make_float4(0.f, 0.f, 0.f, 0.f);
            if (r + lane < r1) {
                int dt;
                float4 ev = comp_e(r - r0 + lane, dt);
                d = dt;
                a4.x = expf(ev.x - m.x) * den.x; a4.y = expf(ev.y - m.y) * den.y;
                a4.z = expf(ev.z - m.z) * den.z; a4.w = expf(ev.w - m.w) * den.w;
            }
            for (int j = 0; j < cnt; ++j) {
                int ddv = __shfl(d, j);
                unsigned lu[W2];
                #pragma unroll
                for (int w = 0; w < W2; ++w)
                    lu[w] = *(const unsigned*)(xbase + (size_t)ddv * Fin + w * 2);
                fma_edge(lu, __shfl(a4.x, j), __shfl(a4.y, j), __shfl(a4.z, j), __shfl(a4.w, j));
            }
        }
    }

    __hip_bfloat16* crow = Cat + (size_t)n * F4;
    #pragma unroll
    for (int h = 0; h < 4; ++h) {
        union { unsigned u[W2]; unsigned short s[CF]; } pk;
        #pragma unroll
        for (int w = 0; w < W2; ++w) {
            pk.s[w * 2 + 0] = f2bf_u16(acc[h][w].x);
            pk.s[w * 2 + 1] = f2bf_u16(acc[h][w].y);
        }
        #pragma unroll
        for (int w = 0; w < W2; ++w)
            *(unsigned*)(crow + h * Fin + lane * CF + w * 2) = pk.u[w];
    }
}

struct AggPair {
    const __hip_bfloat16* Xb[2];
    const float* ssrc[2]; const float* sdst[2];
    __hip_bfloat16* Cat[2];
};

template<int CF0, int CF1>
__global__ __launch_bounds__(256) void agg_pair_kernel(AggPair p,
                                                       const int* __restrict__ row_ptr,
                                                       const int* __restrict__ csr_dst)
{
    if (blockIdx.y == 0)
        agg_body<CF0>(p.Xb[0], p.ssrc[0], p.sdst[0], row_ptr, csr_dst, p.Cat[0]);
    else
        agg_body<CF1>(p.Xb[1], p.ssrc[1], p.sdst[1], row_ptr, csr_dst, p.Cat[1]);
}

// ---------------------------------------------------------------- MFMA GEMM + ELU + SE-pool + optional next scores (bf16-only output)
struct GemmArgs {
    const __hip_bfloat16 *Cat, *Xb, *Wct;
    __hip_bfloat16* xbout;
    const float* wscN; float *ssrcN, *sdstN;
    int F4, FIN, ch;
};
struct GemmPair { GemmArgs g[2]; };

__global__ __launch_bounds__(256) void gemm_pair_kernel(GemmPair p, float* __restrict__ sums)
{
    GemmArgs a = (blockIdx.y == 0) ? p.g[0] : p.g[1];
    const int F4 = a.F4, FIN = a.FIN;
    const int KK = F4 + FIN;
    const int BK = 64;
    const int NIT = KK / BK;
    __shared__ short As[2][32 * 72];
    __shared__ short Bs[2][128 * 72];
    __shared__ float ls[4];
    __shared__ float sred[4][4][4][8];

    int tid = threadIdx.x, lane = tid & 63, wid = tid >> 6;
    int wr = wid >> 1, wc = wid & 1;
    int ar = lane & 15, kg = lane >> 4;
    int row0 = blockIdx.x * 32;

    int a_row = tid >> 3, a_seg = tid & 7;
    int b_col = tid >> 1, b_seg0 = (tid & 1) * 4;

    const __hip_bfloat16* AgC = a.Cat + (size_t)(row0 + a_row) * F4 + a_seg * 8;
    const __hip_bfloat16* AgX = a.Xb + (size_t)(row0 + a_row) * FIN + a_seg * 8;
    const __hip_bfloat16* Bg = a.Wct + (size_t)b_col * KK + b_seg0 * 8;

    short8v fa, fb0, fb1, fb2, fb3;
    f32x4 acc[4] = {};

    fa  = *(const short8v*)(AgC);
    fb0 = *(const short8v*)(Bg);
    fb1 = *(const short8v*)(Bg + 8);
    fb2 = *(const short8v*)(Bg + 16);
    fb3 = *(const short8v*)(Bg + 24);
    *(short8v*)(&As[0][a_row * 72 + a_seg * 8]) = fa;
    *(short8v*)(&Bs[0][b_col * 72 + (b_seg0 + 0) * 8]) = fb0;
    *(short8v*)(&Bs[0][b_col * 72 + (b_seg0 + 1) * 8]) = fb1;
    *(short8v*)(&Bs[0][b_col * 72 + (b_seg0 + 2) * 8]) = fb2;
    *(short8v*)(&Bs[0][b_col * 72 + (b_seg0 + 3) * 8]) = fb3;

    int cur = 0;
    for (int it = 0; it < NIT; ++it) {
        if (it + 1 < NIT) {
            int kb = (it + 1) * BK;
            fa  = (kb < F4) ? *(const short8v*)(AgC + kb) : *(const short8v*)(AgX + (kb - F4));
            fb0 = *(const short8v*)(Bg + kb);
            fb1 = *(const short8v*)(Bg + kb + 8);
            fb2 = *(const short8v*)(Bg + kb + 16);
            fb3 = *(const short8v*)(Bg + kb + 24);
        }
        __syncthreads();
        #pragma unroll
        for (int ks = 0; ks < 2; ++ks) {
            short8v av = *(const short8v*)(&As[cur][(wr * 16 + ar) * 72 + ks * 32 + kg * 8]);
            #pragma unroll
            for (int nb = 0; nb < 4; ++nb) {
                short8v bv = *(const short8v*)(&Bs[cur][(wc * 64 + nb * 16 + ar) * 72 + ks * 32 + kg * 8]);
                acc[nb] = __builtin_amdgcn_mfma_f32_16x16x32_bf16(av, bv, acc[nb], 0, 0, 0);
            }
        }
        if (it + 1 < NIT) {
            int nb2 = cur ^ 1;
            *(short8v*)(&As[nb2][a_row * 72 + a_seg * 8]) = fa;
            *(short8v*)(&Bs[nb2][b_col * 72 + (b_seg0 + 0) * 8]) = fb0;
            *(short8v*)(&Bs[nb2][b_col * 72 + (b_seg0 + 1) * 8]) = fb1;
            *(short8v*)(&Bs[nb2][b_col * 72 + (b_seg0 + 2) * 8]) = fb2;
            *(short8v*)(&Bs[nb2][b_col * 72 + (b_seg0 + 3) * 8]) = fb3;
        }
        cur ^= 1;
    }

    float lsum = 0.f;
    float vpost[4][4];
    int rsub = (lane >> 4) * 4;
    #pragma unroll
    for (int nb = 0; nb < 4; ++nb) {
        int col = wc * 64 + nb * 16 + ar;
        #pragma unroll
        for (int r = 0; r < 4; ++r) {
            int row = row0 + wr * 16 + rsub + r;
            float v = acc[nb][r];
            v = v > 0.f ? v : expm1f(v);
            vpost[nb][r] = v;
            lsum += v;
            a.xbout[(size_t)row * 128 + col] = __float2bfloat16(v);
        }
    }
    #pragma unroll
    for (int o = 32; o; o >>= 1) lsum += __shfl_xor(lsum, o);
    if (lane == 0) ls[wid] = lsum;

    bool dosc = a.wscN != nullptr;
    if (dosc) {
        float sc[4][8] = {};
        #pragma unroll
        for (int j = 0; j < 8; ++j) {
            #pragma unroll
            for (int nb = 0; nb < 4; ++nb) {
                float wv = a.wscN[j * 256 + wc * 64 + nb * 16 + ar];
                #pragma unroll
                for (int r = 0; r < 4; ++r) sc[r][j] += vpost[nb][r] * wv;
            }
        }
        #pragma unroll
        for (int o = 8; o; o >>= 1)
            #pragma unroll
            for (int r = 0; r < 4; ++r)
                #pragma unroll
                for (int j = 0; j < 8; ++j) sc[r][j] += __shfl_xor(sc[r][j], o);
        if (ar == 0) {
            int grp = lane >> 4;
            #pragma unroll
            for (int r = 0; r < 4; ++r)
                #pragma unroll
                for (int j = 0; j < 8; ++j) sred[wid][grp][r][j] = sc[r][j];
        }
    }
    __syncthreads();
    if (tid == 0) atomicAdd(&sums[a.ch], ls[0] + ls[1] + ls[2] + ls[3]);
    if (dosc) {
        int row_local = tid >> 3, j = tid & 7;
        int w_r = row_local >> 4, grp = (row_local >> 2) & 3, r = row_local & 3;
        float total = sred[w_r * 2 + 0][grp][r][j] + sred[w_r * 2 + 1][grp][r][j];
        int row = row0 + row_local;
        if (j < 4) a.ssrcN[(size_t)row * 4 + j] = total;
        else       a.sdstN[(size_t)row * 4 + (j - 4)] = total;
    }
}

// ---------------------------------------------------------------- SE MLP -> att[4] (one tiny dispatch; avoids per-thread MLP in final)
__global__ void att_kernel(const float* __restrict__ sums,
                           const float* __restrict__ fc1w, const float* __restrict__ fc1b,
                           const float* __restrict__ fc2w, const float* __restrict__ fc2b,
                           float* __restrict__ att)
{
    if (threadIdx.x != 0 || blockIdx.x != 0) return;
    float avg[4];
    for (int c = 0; c < 4; ++c) avg[c] = sums[c] * (1.f / (NN * 128.f));
    float z[20];
    for (int j = 0; j < 20; ++j) {
        float v = fc1b[j];
        for (int c = 0; c < 4; ++c) v += avg[c] * fc1w[c * 20 + j];
        z[j] = v;
    }
    for (int c = 0; c < 4; ++c) {
        float v = fc2b[c];
        for (int j = 0; j < 20; ++j) v += z[j] * fc2w[j * 4 + c];
        att[c] = 1.f / (1.f + expf(-v));
    }
}

// ---------------------------------------------------------------- final: relu(att*x) conv, bf16 inputs, 2 elems/thread
__global__ __launch_bounds__(256) void final_kernel(const __hip_bfloat16* __restrict__ x1,
                                                    const __hip_bfloat16* __restrict__ x2,
                                                    const __hip_bfloat16* __restrict__ d1,
                                                    const __hip_bfloat16* __restrict__ d2,
                                                    const float* __restrict__ att4,
                                                    const float* __restrict__ convw,
                                                    const float* __restrict__ convb,
                                                    float* __restrict__ out)
{
    int i = (blockIdx.x * 256 + threadIdx.x) * 2;
    if (i >= NN * 128) return;
    float a0 = att4[0], a1 = att4[1], a2 = att4[2], a3 = att4[3];
    unsigned u1 = *(const unsigned*)(x1 + i);
    unsigned u2 = *(const unsigned*)(x2 + i);
    unsigned u3 = *(const unsigned*)(d1 + i);
    unsigned u4 = *(const unsigned*)(d2 + i);
    float w0 = convw[0], w1 = convw[1], w2 = convw[2], w3 = convw[3];
    float cb = convb[0];
    float2 v1 = bfpair(u1), v2 = bfpair(u2), v3 = bfpair(u3), v4 = bfpair(u4);
    float2 r;
    r.x = cb + w0 * fmaxf(a0 * v1.x, 0.f) + w1 * fmaxf(a1 * v2.x, 0.f)
             + w2 * fmaxf(a2 * v3.x, 0.f) + w3 * fmaxf(a3 * v4.x, 0.f);
    r.y = cb + w0 * fmaxf(a0 * v1.y, 0.f) + w1 * fmaxf(a1 * v2.y, 0.f)
             + w2 * fmaxf(a2 * v3.y, 0.f) + w3 * fmaxf(a3 * v4.y, 0.f);
    *(float2*)(out + i) = r;
}

// ---------------------------------------------------------------- host
extern "C" void kernel_launch(void* const* d_in, const int* in_sizes, int n_in,
                              void* d_out, int out_size, void* d_ws, size_t ws_size,
                              hipStream_t stream)
{
    (void)in_sizes; (void)n_in; (void)out_size; (void)ws_size;
    const float* x    = (const float*)d_in[0];
    const float* dat  = (const float*)d_in[1];
    const float* W1   = (const float*)d_in[2];
    const float* a1s  = (const float*)d_in[3];
    const float* a1d  = (const float*)d_in[4];
    const float* R1   = (const float*)d_in[5];
    const float* W2   = (const float*)d_in[6];
    const float* a2s  = (const float*)d_in[7];
    const float* a2d  = (const float*)d_in[8];
    const float* R2   = (const float*)d_in[9];
    const float* Wd1  = (const float*)d_in[10];
    const float* ad1s = (const float*)d_in[11];
    const float* ad1d = (const float*)d_in[12];
    const float* Rd1  = (const float*)d_in[13];
    const float* Wd2  = (const float*)d_in[14];
    const float* ad2s = (const float*)d_in[15];
    const float* ad2d = (const float*)d_in[16];
    const float* Rd2  = (const float*)d_in[17];
    const float* fc1w = (const float*)d_in[18];
    const float* fc1b = (const float*)d_in[19];
    const float* fc2w = (const float*)d_in[20];
    const float* fc2b = (const float*)d_in[21];
    const float* convw= (const float*)d_in[22];
    const float* convb= (const float*)d_in[23];
    const int*   eidx = (const int*)d_in[24];
    const int* esrc = eidx;
    const int* edst = eidx + EE;
    float* out = (float*)d_out;

    char* base = (char*)d_ws;
    size_t woff = 0;
    auto alloc = [&](size_t bytes) -> void* {
        void* p = base + woff;
        woff = (woff + bytes + 255) & ~(size_t)255;
        return p;
    };
    __hip_bfloat16* Cat0 = (__hip_bfloat16*)alloc((size_t)NN * 1024 * 2);
    __hip_bfloat16* Cat2 = (__hip_bfloat16*)alloc((size_t)NN * 512 * 2);
    __hip_bfloat16* XbX   = (__hip_bfloat16*)alloc((size_t)NN * FXX * 2);
    __hip_bfloat16* XbDat = (__hip_bfloat16*)alloc((size_t)NN * FWW * 2);
    __hip_bfloat16* Xb1   = (__hip_bfloat16*)alloc((size_t)NN * 128 * 2);
    __hip_bfloat16* XbD1  = (__hip_bfloat16*)alloc((size_t)NN * 128 * 2);
    __hip_bfloat16* Xb2   = (__hip_bfloat16*)alloc((size_t)NN * 128 * 2);
    __hip_bfloat16* XbD2  = (__hip_bfloat16*)alloc((size_t)NN * 128 * 2);
    float* Wsc   = (float*)alloc((size_t)4 * 2048 * 4);
    __hip_bfloat16* Wct0 = (__hip_bfloat16*)alloc((size_t)128 * 1280 * 2);
    __hip_bfloat16* Wct1 = (__hip_bfloat16*)alloc((size_t)128 * 640 * 2);
    __hip_bfloat16* Wct2 = (__hip_bfloat16*)alloc((size_t)128 * 640 * 2);
    __hip_bfloat16* Wct3 = (__hip_bfloat16*)alloc((size_t)128 * 640 * 2);
    float* SsrcX = (float*)alloc((size_t)NN * 4 * 4);
    float* SdstX = (float*)alloc((size_t)NN * 4 * 4);
    float* Ssrc1 = (float*)alloc((size_t)NN * 4 * 4);
    float* Sdst1 = (float*)alloc((size_t)NN * 4 * 4);
    float* SsrcD = (float*)alloc((size_t)NN * 4 * 4);
    float* SdstD = (float*)alloc((size_t)NN * 4 * 4);
    float* Ssrc3 = (float*)alloc((size_t)NN * 4 * 4);
    float* Sdst3 = (float*)alloc((size_t)NN * 4 * 4);
    int* RowPtr  = (int*)alloc((size_t)(NN + 1) * 4);
    int* Cnt     = (int*)alloc((size_t)NN * 4);
    int* Off     = (int*)alloc((size_t)NN * 4);
    int* CsrDst  = (int*)alloc((size_t)EE * 4);
    float* Sums  = (float*)alloc(16);
    float* Att   = (float*)alloc(16);

    // setup
    {
        WscParams WP;
        WP.t[0] = { W1,  a1s,  a1d,  FXX };
        WP.t[1] = { W2,  a2s,  a2d,  FWW };
        WP.t[2] = { Wd1, ad1s, ad1d, FWW };
        WP.t[3] = { Wd2, ad2s, ad2d, FWW };
        wsc_kernel<<<dim3(256, 1, 4), 256, 0, stream>>>(WP, Wsc);
        WcParams CP;
        CP.t[0] = { W1,  R1,  Wct0, FXX, 1280, 128 * 1280 };
        CP.t[1] = { W2,  R2,  Wct1, FWW, 640,  128 * 640 };
        CP.t[2] = { Wd1, Rd1, Wct2, FWW, 640,  128 * 640 };
        CP.t[3] = { Wd2, Rd2, Wct3, FWW, 640,  128 * 640 };
        wcomb_kernel<<<dim3(640, 1, 4), 256, 0, stream>>>(CP);
        CSPair CS;
        CS.Xf[0] = x;   CS.Xb[0] = XbX;   CS.wsc[0] = Wsc;            CS.ssrc[0] = SsrcX; CS.sdst[0] = SdstX;
        CS.Xf[1] = dat; CS.Xb[1] = XbDat; CS.wsc[1] = Wsc + 2 * 2048; CS.ssrc[1] = SsrcD; CS.sdst[1] = SdstD;
        cast_score_pair<<<dim3((NN + 3) / 4, 2), 256, 0, stream>>>(CS);
    }
    hipMemsetAsync(Cnt, 0, (size_t)NN * 4, stream);
    hipMemsetAsync(Off, 0, (size_t)NN * 4, stream);
    hipMemsetAsync(Sums, 0, 16, stream);
    hist_kernel<<<(EE + 255) / 256, 256, 0, stream>>>(esrc, Cnt);
    scan_kernel<<<1, 1024, 0, stream>>>(Cnt, RowPtr);
    scatter_kernel<<<(EE + 255) / 256, 256, 0, stream>>>(esrc, edst, RowPtr, Off, CsrDst);

    // stage A: agg layers {0, 2}
    {
        AggPair AP;
        AP.Xb[0] = XbX;   AP.ssrc[0] = SsrcX; AP.sdst[0] = SdstX; AP.Cat[0] = Cat0;
        AP.Xb[1] = XbDat; AP.ssrc[1] = SsrcD; AP.sdst[1] = SdstD; AP.Cat[1] = Cat2;
        agg_pair_kernel<4, 2><<<dim3((NN + 3) / 4, 2), 256, 0, stream>>>(AP, RowPtr, CsrDst);
    }
    // stage B: gemm layers {0, 2} (+ next-layer scores)
    {
        GemmPair GP;
        GP.g[0] = { Cat0, XbX,   Wct0, Xb1,  Wsc + 1 * 2048, Ssrc1, Sdst1, 1024, 256, 0 };
        GP.g[1] = { Cat2, XbDat, Wct2, XbD1, Wsc + 3 * 2048, Ssrc3, Sdst3, 512,  128, 2 };
        gemm_pair_kernel<<<dim3(NN / 32, 2), 256, 0, stream>>>(GP, Sums);
    }
    // stage C: agg layers {1, 3}
    {
        AggPair AP;
        AP.Xb[0] = Xb1;  AP.ssrc[0] = Ssrc1; AP.sdst[0] = Sdst1; AP.Cat[0] = Cat0;
        AP.Xb[1] = XbD1; AP.ssrc[1] = Ssrc3; AP.sdst[1] = Sdst3; AP.Cat[1] = Cat2;
        agg_pair_kernel<2, 2><<<dim3((NN + 3) / 4, 2), 256, 0, stream>>>(AP, RowPtr, CsrDst);
    }
    // stage D: gemm layers {1, 3}
    {
        GemmPair GP;
        GP.g[0] = { Cat0, Xb1,  Wct1, Xb2,  nullptr, nullptr, nullptr, 512, 128, 1 };
        GP.g[1] = { Cat2, XbD1, Wct3, XbD2, nullptr, nullptr, nullptr, 512, 128, 3 };
        gemm_pair_kernel<<<dim3(NN / 32, 2), 256, 0, stream>>>(GP, Sums);
    }

    att_kernel<<<1, 64, 0, stream>>>(Sums, fc1w, fc1b, fc2w, fc2b, Att);
    final_kernel<<<(NN * 128 / 2 + 255) / 256, 256, 0, stream>>>(Xb1, Xb2, XbD1, XbD2, Att,
                                                                 convw, convb, out);
}

// Round 19
// 294.850 us; speedup vs baseline: 1.0931x; 1.0192x over previous
//
#include <hip/hip_runtime.h>
#include <hip/hip_bf16.h>
#include <math.h>

#define NN 20000
#define EE 320000
#define FXX 256
#define FWW 128
#define NH 4

typedef __attribute__((ext_vector_type(8))) short short8v;
typedef __attribute__((ext_vector_type(4))) float f32x4;

static __device__ __forceinline__ float bf2f(unsigned short s) {
    unsigned int u = ((unsigned int)s) << 16;
    return __builtin_bit_cast(float, u);
}

static __device__ __forceinline__ unsigned short f2bf_u16(float f) {
    unsigned int u = __builtin_bit_cast(unsigned int, f);
    unsigned int r = 0x7fffu + ((u >> 16) & 1u);
    return (unsigned short)((u + r) >> 16);
}

static __device__ __forceinline__ float2 bfpair(unsigned u) {
    float lo = __builtin_bit_cast(float, u << 16);
    float hi = __builtin_bit_cast(float, u & 0xFFFF0000u);
    return make_float2(lo, hi);
}

// ---------------------------------------------------------------- wsc: w~ = W_h @ a (score projection vectors), fp32
struct WscItem { const float* W; const float* as_; const float* ad_; int Fin; };
struct WscParams { WscItem t[4]; };

__global__ __launch_bounds__(256) void wsc_kernel(WscParams p, float* __restrict__ wsc)
{
    int L = blockIdx.x >> 8, bx = blockIdx.x & 255;
    WscItem it = p.t[L];
    int wid = threadIdx.x >> 6, lane = threadIdx.x & 63;
    int r = bx * 4 + wid;
    if (r >= it.Fin * 4) return;
    int h = r / it.Fin, k = r - h * it.Fin;
    float2 w2 = *(const float2*)(it.W + ((size_t)(h * it.Fin + k)) * 128 + 2 * lane);
    float2 s2 = *(const float2*)(it.as_ + h * 128 + 2 * lane);
    float2 d2 = *(const float2*)(it.ad_ + h * 128 + 2 * lane);
    float vs = w2.x * s2.x + w2.y * s2.y;
    float vd = w2.x * d2.x + w2.y * d2.y;
    #pragma unroll
    for (int o = 32; o; o >>= 1) { vs += __shfl_xor(vs, o); vd += __shfl_xor(vd, o); }
    if (lane == 0) {
        wsc[(size_t)L * 2048 + h * 256 + k] = vs;
        wsc[(size_t)L * 2048 + (4 + h) * 256 + k] = vd;
    }
}

// ---------------------------------------------------------------- prologue bodies (post-wsc)
static __device__ void wcomb_body(int bx, const float* __restrict__ W, const float* __restrict__ R,
                                  __hip_bfloat16* __restrict__ dst, int Fin, int KK, int total)
{
    int idx = bx * 256 + threadIdx.x;
    if (idx >= total) return;
    int c = idx / KK;
    int k5 = idx - c * KK;
    int f4 = Fin * 4;
    float v;
    if (k5 < f4) {
        int h = k5 / Fin, k = k5 - h * Fin;
        v = 0.25f * W[((size_t)(h * Fin + k)) * 128 + c];
    } else {
        v = R[(size_t)(k5 - f4) * 128 + c];
    }
    dst[(size_t)c * KK + k5] = __float2bfloat16(v);
}

template<int CF>
static __device__ void cast_score_body(int bx,
                                       const float* __restrict__ Xf,
                                       __hip_bfloat16* __restrict__ Xb,
                                       const float* __restrict__ wsc,
                                       float* __restrict__ ssrc,
                                       float* __restrict__ sdst)
{
    const int Fin = CF * 64;
    int wid = threadIdx.x >> 6, lane = threadIdx.x & 63;
    int n = bx * 4 + wid;
    if (n >= NN) return;
    int c0 = lane * CF;
    float xv[CF];
    #pragma unroll
    for (int i = 0; i < CF; ++i) xv[i] = Xf[(size_t)n * Fin + c0 + i];
    union { unsigned u[CF / 2]; unsigned short s[CF]; } pk;
    #pragma unroll
    for (int i = 0; i < CF; ++i) pk.s[i] = f2bf_u16(xv[i]);
    #pragma unroll
    for (int w = 0; w < CF / 2; ++w)
        *(unsigned*)(Xb + (size_t)n * Fin + c0 + w * 2) = pk.u[w];
    float acc[8];
    #pragma unroll
    for (int j = 0; j < 8; ++j) {
        const float* w = wsc + j * 256 + c0;
        float s = 0.f;
        #pragma unroll
        for (int i = 0; i < CF; ++i) s += xv[i] * w[i];
        acc[j] = s;
    }
    #pragma unroll
    for (int o = 32; o; o >>= 1)
        #pragma unroll
        for (int j = 0; j < 8; ++j) acc[j] += __shfl_xor(acc[j], o);
    if (lane == 0) {
        *(float4*)(ssrc + (size_t)n * 4) = make_float4(acc[0], acc[1], acc[2], acc[3]);
        *(float4*)(sdst + (size_t)n * 4) = make_float4(acc[4], acc[5], acc[6], acc[7]);
    }
}

// mega-prologue (after wsc): wcomb(2560) | cast_score(10000) | hist(1250)
struct MegaArgs {
    const float *W[4], *R[4];
    __hip_bfloat16* Wct[4];
    int Fin[4], KK[4];
    const float* wsc;
    const float *xf, *datf;
    __hip_bfloat16 *XbX, *XbDat;
    float *SsrcX, *SdstX, *SsrcD, *SdstD;
    const int* esrc;
    int* cnt;
};

__global__ __launch_bounds__(256) void mega_prologue(MegaArgs a)
{
    int bid = blockIdx.x;
    if (bid < 2560) {
        int L = bid / 640, bx = bid - L * 640;
        wcomb_body(bx, a.W[L], a.R[L], a.Wct[L], a.Fin[L], a.KK[L], 128 * a.KK[L]);
    } else if (bid < 2560 + 10000) {
        int idx = bid - 2560;
        if (idx < 5000)
            cast_score_body<4>(idx, a.xf, a.XbX, a.wsc, a.SsrcX, a.SdstX);
        else
            cast_score_body<2>(idx - 5000, a.datf, a.XbDat, a.wsc + 2 * 2048, a.SsrcD, a.SdstD);
    } else {
        int idx = bid - (2560 + 10000);
        int i = idx * 256 + threadIdx.x;
        if (i < EE) atomicAdd(&a.cnt[a.esrc[i]], 1);
    }
}

// ---------------------------------------------------------------- CSR scan + scatter
__global__ __launch_bounds__(1024) void scan_kernel(const int* __restrict__ cnt, int* __restrict__ row_ptr)
{
    __shared__ int lds[1024];
    int t = threadIdx.x;
    const int CH = 20;
    int start = t * CH, end = start + CH; if (end > NN) end = NN;
    int sum = 0;
    if (start < NN) for (int i = start; i < end; ++i) sum += cnt[i];
    lds[t] = sum;
    __syncthreads();
    for (int o = 1; o < 1024; o <<= 1) {
        int v = (t >= o) ? lds[t - o] : 0;
        __syncthreads();
        lds[t] += v;
        __syncthreads();
    }
    int run = lds[t] - sum;
    if (start < NN) for (int i = start; i < end; ++i) { row_ptr[i] = run; run += cnt[i]; }
    if (t == 1023) row_ptr[NN] = lds[1023];
}

__global__ __launch_bounds__(256) void scatter_kernel(const int* __restrict__ src,
                                                      const int* __restrict__ dst,
                                                      const int* __restrict__ row_ptr,
                                                      int* __restrict__ off,
                                                      int* __restrict__ csr_dst)
{
    int i = blockIdx.x * blockDim.x + threadIdx.x;
    if (i >= EE) return;
    int s = src[i];
    int p = row_ptr[s] + atomicAdd(&off[s], 1);
    csr_dst[p] = dst[i];
}

// ---------------------------------------------------------------- FUSED softmax + aggregate body (float2-packed FMA)
template<int CF>
static __device__ __forceinline__ void agg_body(const __hip_bfloat16* __restrict__ Xb,
                                                const float* __restrict__ ssrc,
                                                const float* __restrict__ sdst,
                                                const int* __restrict__ row_ptr,
                                                const int* __restrict__ csr_dst,
                                                __hip_bfloat16* __restrict__ Cat)
{
    const int Fin = CF * 64, F4 = 4 * Fin;
    const int W2 = CF / 2;
    int wid = threadIdx.x >> 6, lane = threadIdx.x & 63;
    int n = blockIdx.x * 4 + wid;
    if (n >= NN) return;
    int r0 = row_ptr[n], r1 = row_ptr[n + 1];
    int deg = r1 - r0;

    float2 acc[4][W2] = {};
    const __hip_bfloat16* xbase = Xb + lane * CF;

    if (deg > 0) {
        float4 sn = *(const float4*)(ssrc + (size_t)n * 4);
        auto comp_e = [&](int s, int& dout) -> float4 {
            int d = csr_dst[r0 + s];
            dout = d;
            float4 sd = *(const float4*)(sdst + (size_t)d * 4);
            float4 e; float v;
            v = sn.x + sd.x; e.x = v >= 0.f ? v : 0.2f * v;
            v = sn.y + sd.y; e.y = v >= 0.f ? v : 0.2f * v;
            v = sn.z + sd.z; e.z = v >= 0.f ? v : 0.2f * v;
            v = sn.w + sd.w; e.w = v >= 0.f ? v : 0.2f * v;
            return e;
        };

        float4 e0 = make_float4(-1e30f, -1e30f, -1e30f, -1e30f);
        int d0 = 0;
        if (lane < deg) e0 = comp_e(lane, d0);
        float4 m = e0;
        for (int s = lane + 64; s < deg; s += 64) {
            int dt; float4 ev = comp_e(s, dt);
            m.x = fmaxf(m.x, ev.x); m.y = fmaxf(m.y, ev.y);
            m.z = fmaxf(m.z, ev.z); m.w = fmaxf(m.w, ev.w);
        }
        #pragma unroll
        for (int o = 32; o; o >>= 1) {
            m.x = fmaxf(m.x, __shfl_xor(m.x, o));
            m.y = fmaxf(m.y, __shfl_xor(m.y, o));
            m.z = fmaxf(m.z, __shfl_xor(m.z, o));
            m.w = fmaxf(m.w, __shfl_xor(m.w, o));
        }
        float4 p0 = make_float4(0.f, 0.f, 0.f, 0.f);
        if (lane < deg) {
            p0.x = expf(e0.x - m.x); p0.y = expf(e0.y - m.y);
            p0.z = expf(e0.z - m.z); p0.w = expf(e0.w - m.w);
        }
        float4 den = p0;
        for (int s = lane + 64; s < deg; s += 64) {
            int dt; float4 ev = comp_e(s, dt);
            den.x += expf(ev.x - m.x); den.y += expf(ev.y - m.y);
            den.z += expf(ev.z - m.z); den.w += expf(ev.w - m.w);
        }
        #pragma unroll
        for (int o = 32; o; o >>= 1) {
            den.x += __shfl_xor(den.x, o); den.y += __shfl_xor(den.y, o);
            den.z += __shfl_xor(den.z, o); den.w += __shfl_xor(den.w, o);
        }
        den.x = 1.f / (den.x + 1e-16f); den.y = 1.f / (den.y + 1e-16f);
        den.z = 1.f / (den.z + 1e-16f); den.w = 1.f / (den.w + 1e-16f);

        float4 a0;
        a0.x = p0.x * den.x; a0.y = p0.y * den.y;
        a0.z = p0.z * den.z; a0.w = p0.w * den.w;

        auto fma_edge = [&](const unsigned (&u)[W2], float ax, float ay, float az, float aw) {
            #pragma unroll
            for (int w = 0; w < W2; ++w) {
                float2 xv = bfpair(u[w]);
                acc[0][w].x += ax * xv.x; acc[0][w].y += ax * xv.y;
                acc[1][w].x += ay * xv.x; acc[1][w].y += ay * xv.y;
                acc[2][w].x += az * xv.x; acc[2][w].y += az * xv.y;
                acc[3][w].x += aw * xv.x; acc[3][w].y += aw * xv.y;
            }
        };

        int cnt0 = min(deg, 64);
        int last = cnt0 - 1;
        for (int base = 0; base < cnt0; base += 4) {
            int j1 = min(base + 1, last), j2 = min(base + 2, last), j3 = min(base + 3, last);
            int dv0 = __shfl(d0, base), dv1 = __shfl(d0, j1);
            int dv2 = __shfl(d0, j2),   dv3 = __shfl(d0, j3);
            unsigned l0[W2], l1[W2], l2[W2], l3[W2];
            #pragma unroll
            for (int w = 0; w < W2; ++w)
                l0[w] = *(const unsigned*)(xbase + (size_t)dv0 * Fin + w * 2);
            #pragma unroll
            for (int w = 0; w < W2; ++w)
                l1[w] = *(const unsigned*)(xbase + (size_t)dv1 * Fin + w * 2);
            #pragma unroll
            for (int w = 0; w < W2; ++w)
                l2[w] = *(const unsigned*)(xbase + (size_t)dv2 * Fin + w * 2);
            #pragma unroll
            for (int w = 0; w < W2; ++w)
                l3[w] = *(const unsigned*)(xbase + (size_t)dv3 * Fin + w * 2);

            fma_edge(l0, __shfl(a0.x, base), __shfl(a0.y, base), __shfl(a0.z, base), __shfl(a0.w, base));
            if (base + 1 < cnt0)
                fma_edge(l1, __shfl(a0.x, j1), __shfl(a0.y, j1), __shfl(a0.z, j1), __shfl(a0.w, j1));
            if (base + 2 < cnt0)
                fma_edge(l2, __shfl(a0.x, j2), __shfl(a0.y, j2), __shfl(a0.z, j2), __shfl(a0.w, j2));
            if (base + 3 < cnt0)
                fma_edge(l3, __shfl(a0.x, j3), __shfl(a0.y, j3), __shfl(a0.z, j3), __shfl(a0.w, j3));
        }

        for (int r = r0 + 64; r < r1; r += 64) {
            int cnt = min(64, r1 - r);
            int d = 0;
            float4 a4 = make_float4(0.f, 0.f, 0.f, 0.f);
            if (r + lane < r1) {
                int dt;
                float4 ev = comp_e(r - r0 + lane, dt);
                d = dt;
                a4.x = expf(ev.x - m.x) * den.x; a4.y = expf(ev.y - m.y) * den.y;
                a4.z = expf(ev.z - m.z) * den.z; a4.w = expf(ev.w - m.w) * den.w;
            }
            for (int j = 0; j < cnt; ++j) {
                int ddv = __shfl(d, j);
                unsigned lu[W2];
                #pragma unroll
                for (int w = 0; w < W2; ++w)
                    lu[w] = *(const unsigned*)(xbase + (size_t)ddv * Fin + w * 2);
                fma_edge(lu, __shfl(a4.x, j), __shfl(a4.y, j), __shfl(a4.z, j), __shfl(a4.w, j));
            }
        }
    }

    __hip_bfloat16* crow = Cat + (size_t)n * F4;
    #pragma unroll
    for (int h = 0; h < 4; ++h) {
        union { unsigned u[W2]; unsigned short s[CF]; } pk;
        #pragma unroll
        for (int w = 0; w < W2; ++w) {
            pk.s[w * 2 + 0] = f2bf_u16(acc[h][w].x);
            pk.s[w * 2 + 1] = f2bf_u16(acc[h][w].y);
        }
        #pragma unroll
        for (int w = 0; w < W2; ++w)
            *(unsigned*)(crow + h * Fin + lane * CF + w * 2) = pk.u[w];
    }
}

struct AggPair {
    const __hip_bfloat16* Xb[2];
    const float* ssrc[2]; const float* sdst[2];
    __hip_bfloat16* Cat[2];
};

template<int CF0, int CF1>
__global__ __launch_bounds__(256) void agg_pair_kernel(AggPair p,
                                                       const int* __restrict__ row_ptr,
                                                       const int* __restrict__ csr_dst)
{
    if (blockIdx.y == 0)
        agg_body<CF0>(p.Xb[0], p.ssrc[0], p.sdst[0], row_ptr, csr_dst, p.Cat[0]);
    else
        agg_body<CF1>(p.Xb[1], p.ssrc[1], p.sdst[1], row_ptr, csr_dst, p.Cat[1]);
}

// ---------------------------------------------------------------- MFMA GEMM + ELU + SE-pool + optional next scores (bf16-only output)
struct GemmArgs {
    const __hip_bfloat16 *Cat, *Xb, *Wct;
    __hip_bfloat16* xbout;
    const float* wscN; float *ssrcN, *sdstN;
    int F4, FIN, ch;
};
struct GemmPair { GemmArgs g[2]; };

__global__ __launch_bounds__(256) void gemm_pair_kernel(GemmPair p, float* __restrict__ sums)
{
    GemmArgs a = (blockIdx.y == 0) ? p.g[0] : p.g[1];
    const int F4 = a.F4, FIN = a.FIN;
    const int KK = F4 + FIN;
    const int BK = 64;
    const int NIT = KK / BK;
    __shared__ short As[2][32 * 72];
    __shared__ short Bs[2][128 * 72];
    __shared__ float ls[4];
    __shared__ float sred[4][4][4][8];

    int tid = threadIdx.x, lane = tid & 63, wid = tid >> 6;
    int wr = wid >> 1, wc = wid & 1;
    int ar = lane & 15, kg = lane >> 4;
    int row0 = blockIdx.x * 32;

    int a_row = tid >> 3, a_seg = tid & 7;
    int b_col = tid >> 1, b_seg0 = (tid & 1) * 4;

    const __hip_bfloat16* AgC = a.Cat + (size_t)(row0 + a_row) * F4 + a_seg * 8;
    const __hip_bfloat16* AgX = a.Xb + (size_t)(row0 + a_row) * FIN + a_seg * 8;
    const __hip_bfloat16* Bg = a.Wct + (size_t)b_col * KK + b_seg0 * 8;

    short8v fa, fb0, fb1, fb2, fb3;
    f32x4 acc[4] = {};

    fa  = *(const short8v*)(AgC);
    fb0 = *(const short8v*)(Bg);
    fb1 = *(const short8v*)(Bg + 8);
    fb2 = *(const short8v*)(Bg + 16);
    fb3 = *(const short8v*)(Bg + 24);
    *(short8v*)(&As[0][a_row * 72 + a_seg * 8]) = fa;
    *(short8v*)(&Bs[0][b_col * 72 + (b_seg0 + 0) * 8]) = fb0;
    *(short8v*)(&Bs[0][b_col * 72 + (b_seg0 + 1) * 8]) = fb1;
    *(short8v*)(&Bs[0][b_col * 72 + (b_seg0 + 2) * 8]) = fb2;
    *(short8v*)(&Bs[0][b_col * 72 + (b_seg0 + 3) * 8]) = fb3;

    int cur = 0;
    for (int it = 0; it < NIT; ++it) {
        if (it + 1 < NIT) {
            int kb = (it + 1) * BK;
            fa  = (kb < F4) ? *(const short8v*)(AgC + kb) : *(const short8v*)(AgX + (kb - F4));
            fb0 = *(const short8v*)(Bg + kb);
            fb1 = *(const short8v*)(Bg + kb + 8);
            fb2 = *(const short8v*)(Bg + kb + 16);
            fb3 = *(const short8v*)(Bg + kb + 24);
        }
        __syncthreads();
        #pragma unroll
        for (int ks = 0; ks < 2; ++ks) {
            short8v av = *(const short8v*)(&As[cur][(wr * 16 + ar) * 72 + ks * 32 + kg * 8]);
            #pragma unroll
            for (int nb = 0; nb < 4; ++nb) {
                short8v bv = *(const short8v*)(&Bs[cur][(wc * 64 + nb * 16 + ar) * 72 + ks * 32 + kg * 8]);
                acc[nb] = __builtin_amdgcn_mfma_f32_16x16x32_bf16(av, bv, acc[nb], 0, 0, 0);
            }
        }
        if (it + 1 < NIT) {
            int nb2 = cur ^ 1;
            *(short8v*)(&As[nb2][a_row * 72 + a_seg * 8]) = fa;
            *(short8v*)(&Bs[nb2][b_col * 72 + (b_seg0 + 0) * 8]) = fb0;
            *(short8v*)(&Bs[nb2][b_col * 72 + (b_seg0 + 1) * 8]) = fb1;
            *(short8v*)(&Bs[nb2][b_col * 72 + (b_seg0 + 2) * 8]) = fb2;
            *(short8v*)(&Bs[nb2][b_col * 72 + (b_seg0 + 3) * 8]) = fb3;
        }
        cur ^= 1;
    }

    float lsum = 0.f;
    float vpost[4][4];
    int rsub = (lane >> 4) * 4;
    #pragma unroll
    for (int nb = 0; nb < 4; ++nb) {
        int col = wc * 64 + nb * 16 + ar;
        #pragma unroll
        for (int r = 0; r < 4; ++r) {
            int row = row0 + wr * 16 + rsub + r;
            float v = acc[nb][r];
            v = v > 0.f ? v : expm1f(v);
            vpost[nb][r] = v;
            lsum += v;
            a.xbout[(size_t)row * 128 + col] = __float2bfloat16(v);
        }
    }
    #pragma unroll
    for (int o = 32; o; o >>= 1) lsum += __shfl_xor(lsum, o);
    if (lane == 0) ls[wid] = lsum;

    bool dosc = a.wscN != nullptr;
    if (dosc) {
        float sc[4][8] = {};
        #pragma unroll
        for (int j = 0; j < 8; ++j) {
            #pragma unroll
            for (int nb = 0; nb < 4; ++nb) {
                float wv = a.wscN[j * 256 + wc * 64 + nb * 16 + ar];
                #pragma unroll
                for (int r = 0; r < 4; ++r) sc[r][j] += vpost[nb][r] * wv;
            }
        }
        #pragma unroll
        for (int o = 8; o; o >>= 1)
            #pragma unroll
            for (int r = 0; r < 4; ++r)
                #pragma unroll
                for (int j = 0; j < 8; ++j) sc[r][j] += __shfl_xor(sc[r][j], o);
        if (ar == 0) {
            int grp = lane >> 4;
            #pragma unroll
            for (int r = 0; r < 4; ++r)
                #pragma unroll
                for (int j = 0; j < 8; ++j) sred[wid][grp][r][j] = sc[r][j];
        }
    }
    __syncthreads();
    if (tid == 0) atomicAdd(&sums[a.ch], ls[0] + ls[1] + ls[2] + ls[3]);
    if (dosc) {
        int row_local = tid >> 3, j = tid & 7;
        int w_r = row_local >> 4, grp = (row_local >> 2) & 3, r = row_local & 3;
        float total = sred[w_r * 2 + 0][grp][r][j] + sred[w_r * 2 + 1][grp][r][j];
        int row = row0 + row_local;
        if (j < 4) a.ssrcN[(size_t)row * 4 + j] = total;
        else       a.sdstN[(size_t)row * 4 + (j - 4)] = total;
    }
}

// ---------------------------------------------------------------- SE MLP -> att[4]
__global__ void att_kernel(const float* __restrict__ sums,
                           const float* __restrict__ fc1w, const float* __restrict__ fc1b,
                           const float* __restrict__ fc2w, const float* __restrict__ fc2b,
                           float* __restrict__ att)
{
    if (threadIdx.x != 0 || blockIdx.x != 0) return;
    float avg[4];
    for (int c = 0; c < 4; ++c) avg[c] = sums[c] * (1.f / (NN * 128.f));
    float z[20];
    for (int j = 0; j < 20; ++j) {
        float v = fc1b[j];
        for (int c = 0; c < 4; ++c) v += avg[c] * fc1w[c * 20 + j];
        z[j] = v;
    }
    for (int c = 0; c < 4; ++c) {
        float v = fc2b[c];
        for (int j = 0; j < 20; ++j) v += z[j] * fc2w[j * 4 + c];
        att[c] = 1.f / (1.f + expf(-v));
    }
}

// ---------------------------------------------------------------- final: relu(att*x) conv, bf16 inputs, 2 elems/thread
__global__ __launch_bounds__(256) void final_kernel(const __hip_bfloat16* __restrict__ x1,
                                                    const __hip_bfloat16* __restrict__ x2,
                                                    const __hip_bfloat16* __restrict__ d1,
                                                    const __hip_bfloat16* __restrict__ d2,
                                                    const float* __restrict__ att4,
                                                    const float* __restrict__ convw,
                                                    const float* __restrict__ convb,
                                                    float* __restrict__ out)
{
    int i = (blockIdx.x * 256 + threadIdx.x) * 2;
    if (i >= NN * 128) return;
    float a0 = att4[0], a1 = att4[1], a2 = att4[2], a3 = att4[3];
    unsigned u1 = *(const unsigned*)(x1 + i);
    unsigned u2 = *(const unsigned*)(x2 + i);
    unsigned u3 = *(const unsigned*)(d1 + i);
    unsigned u4 = *(const unsigned*)(d2 + i);
    float w0 = convw[0], w1 = convw[1], w2 = convw[2], w3 = convw[3];
    float cb = convb[0];
    float2 v1 = bfpair(u1), v2 = bfpair(u2), v3 = bfpair(u3), v4 = bfpair(u4);
    float2 r;
    r.x = cb + w0 * fmaxf(a0 * v1.x, 0.f) + w1 * fmaxf(a1 * v2.x, 0.f)
             + w2 * fmaxf(a2 * v3.x, 0.f) + w3 * fmaxf(a3 * v4.x, 0.f);
    r.y = cb + w0 * fmaxf(a0 * v1.y, 0.f) + w1 * fmaxf(a1 * v2.y, 0.f)
             + w2 * fmaxf(a2 * v3.y, 0.f) + w3 * fmaxf(a3 * v4.y, 0.f);
    *(float2*)(out + i) = r;
}

// ---------------------------------------------------------------- host
extern "C" void kernel_launch(void* const* d_in, const int* in_sizes, int n_in,
                              void* d_out, int out_size, void* d_ws, size_t ws_size,
                              hipStream_t stream)
{
    (void)in_sizes; (void)n_in; (void)out_size; (void)ws_size;
    const float* x    = (const float*)d_in[0];
    const float* dat  = (const float*)d_in[1];
    const float* W1   = (const float*)d_in[2];
    const float* a1s  = (const float*)d_in[3];
    const float* a1d  = (const float*)d_in[4];
    const float* R1   = (const float*)d_in[5];
    const float* W2   = (const float*)d_in[6];
    const float* a2s  = (const float*)d_in[7];
    const float* a2d  = (const float*)d_in[8];
    const float* R2   = (const float*)d_in[9];
    const float* Wd1  = (const float*)d_in[10];
    const float* ad1s = (const float*)d_in[11];
    const float* ad1d = (const float*)d_in[12];
    const float* Rd1  = (const float*)d_in[13];
    const float* Wd2  = (const float*)d_in[14];
    const float* ad2s = (const float*)d_in[15];
    const float* ad2d = (const float*)d_in[16];
    const float* Rd2  = (const float*)d_in[17];
    const float* fc1w = (const float*)d_in[18];
    const float* fc1b = (const float*)d_in[19];
    const float* fc2w = (const float*)d_in[20];
    const float* fc2b = (const float*)d_in[21];
    const float* convw= (const float*)d_in[22];
    const float* convb= (const float*)d_in[23];
    const int*   eidx = (const int*)d_in[24];
    const int* esrc = eidx;
    const int* edst = eidx + EE;
    float* out = (float*)d_out;

    char* base = (char*)d_ws;
    size_t woff = 0;
    auto alloc = [&](size_t bytes) -> void* {
        void* p = base + woff;
        woff = (woff + bytes + 255) & ~(size_t)255;
        return p;
    };
    __hip_bfloat16* Cat0 = (__hip_bfloat16*)alloc((size_t)NN * 1024 * 2);
    __hip_bfloat16* Cat2 = (__hip_bfloat16*)alloc((size_t)NN * 512 * 2);
    __hip_bfloat16* XbX   = (__hip_bfloat16*)alloc((size_t)NN * FXX * 2);
    __hip_bfloat16* XbDat = (__hip_bfloat16*)alloc((size_t)NN * FWW * 2);
    __hip_bfloat16* Xb1   = (__hip_bfloat16*)alloc((size_t)NN * 128 * 2);
    __hip_bfloat16* XbD1  = (__hip_bfloat16*)alloc((size_t)NN * 128 * 2);
    __hip_bfloat16* Xb2   = (__hip_bfloat16*)alloc((size_t)NN * 128 * 2);
    __hip_bfloat16* XbD2  = (__hip_bfloat16*)alloc((size_t)NN * 128 * 2);
    float* Wsc   = (float*)alloc((size_t)4 * 2048 * 4);
    __hip_bfloat16* Wct0 = (__hip_bfloat16*)alloc((size_t)128 * 1280 * 2);
    __hip_bfloat16* Wct1 = (__hip_bfloat16*)alloc((size_t)128 * 640 * 2);
    __hip_bfloat16* Wct2 = (__hip_bfloat16*)alloc((size_t)128 * 640 * 2);
    __hip_bfloat16* Wct3 = (__hip_bfloat16*)alloc((size_t)128 * 640 * 2);
    float* SsrcX = (float*)alloc((size_t)NN * 4 * 4);
    float* SdstX = (float*)alloc((size_t)NN * 4 * 4);
    float* Ssrc1 = (float*)alloc((size_t)NN * 4 * 4);
    float* Sdst1 = (float*)alloc((size_t)NN * 4 * 4);
    float* SsrcD = (float*)alloc((size_t)NN * 4 * 4);
    float* SdstD = (float*)alloc((size_t)NN * 4 * 4);
    float* Ssrc3 = (float*)alloc((size_t)NN * 4 * 4);
    float* Sdst3 = (float*)alloc((size_t)NN * 4 * 4);
    int* RowPtr  = (int*)alloc((size_t)(NN + 1) * 4);
    int* Cnt     = (int*)alloc((size_t)NN * 4);
    int* Off     = (int*)alloc((size_t)NN * 4);
    int* CsrDst  = (int*)alloc((size_t)EE * 4);
    float* Sums  = (float*)alloc(16);
    float* Att   = (float*)alloc(16);

    // memsets first (hist runs inside mega_prologue)
    hipMemsetAsync(Cnt, 0, (size_t)NN * 4, stream);
    hipMemsetAsync(Off, 0, (size_t)NN * 4, stream);
    hipMemsetAsync(Sums, 0, 16, stream);

    // wsc first (cast_score depends on it)
    {
        WscParams WP;
        WP.t[0] = { W1,  a1s,  a1d,  FXX };
        WP.t[1] = { W2,  a2s,  a2d,  FWW };
        WP.t[2] = { Wd1, ad1s, ad1d, FWW };
        WP.t[3] = { Wd2, ad2s, ad2d, FWW };
        wsc_kernel<<<1024, 256, 0, stream>>>(WP, Wsc);
    }
    // mega prologue: wcomb | cast_score(x2) | hist  (13810 blocks)
    {
        MegaArgs MA;
        MA.W[0] = W1;  MA.R[0] = R1;  MA.Wct[0] = Wct0; MA.Fin[0] = FXX; MA.KK[0] = 1280;
        MA.W[1] = W2;  MA.R[1] = R2;  MA.Wct[1] = Wct1; MA.Fin[1] = FWW; MA.KK[1] = 640;
        MA.W[2] = Wd1; MA.R[2] = Rd1; MA.Wct[2] = Wct2; MA.Fin[2] = FWW; MA.KK[2] = 640;
        MA.W[3] = Wd2; MA.R[3] = Rd2; MA.Wct[3] = Wct3; MA.Fin[3] = FWW; MA.KK[3] = 640;
        MA.wsc = Wsc;
        MA.xf = x; MA.datf = dat;
        MA.XbX = XbX; MA.XbDat = XbDat;
        MA.SsrcX = SsrcX; MA.SdstX = SdstX; MA.SsrcD = SsrcD; MA.SdstD = SdstD;
        MA.esrc = esrc; MA.cnt = Cnt;
        mega_prologue<<<2560 + 10000 + 1250, 256, 0, stream>>>(MA);
    }
    scan_kernel<<<1, 1024, 0, stream>>>(Cnt, RowPtr);
    scatter_kernel<<<(EE + 255) / 256, 256, 0, stream>>>(esrc, edst, RowPtr, Off, CsrDst);

    // stage A: agg layers {0, 2}
    {
        AggPair AP;
        AP.Xb[0] = XbX;   AP.ssrc[0] = SsrcX; AP.sdst[0] = SdstX; AP.Cat[0] = Cat0;
        AP.Xb[1] = XbDat; AP.ssrc[1] = SsrcD; AP.sdst[1] = SdstD; AP.Cat[1] = Cat2;
        agg_pair_kernel<4, 2><<<dim3((NN + 3) / 4, 2), 256, 0, stream>>>(AP, RowPtr, CsrDst);
    }
    // stage B: gemm layers {0, 2} (+ next-layer scores)
    {
        GemmPair GP;
        GP.g[0] = { Cat0, XbX,   Wct0, Xb1,  Wsc + 1 * 2048, Ssrc1, Sdst1, 1024, 256, 0 };
        GP.g[1] = { Cat2, XbDat, Wct2, XbD1, Wsc + 3 * 2048, Ssrc3, Sdst3, 512,  128, 2 };
        gemm_pair_kernel<<<dim3(NN / 32, 2), 256, 0, stream>>>(GP, Sums);
    }
    // stage C: agg layers {1, 3}
    {
        AggPair AP;
        AP.Xb[0] = Xb1;  AP.ssrc[0] = Ssrc1; AP.sdst[0] = Sdst1; AP.Cat[0] = Cat0;
        AP.Xb[1] = XbD1; AP.ssrc[1] = Ssrc3; AP.sdst[1] = Sdst3; AP.Cat[1] = Cat2;
        agg_pair_kernel<2, 2><<<dim3((NN + 3) / 4, 2), 256, 0, stream>>>(AP, RowPtr, CsrDst);
    }
    // stage D: gemm layers {1, 3}
    {
        GemmPair GP;
        GP.g[0] = { Cat0, Xb1,  Wct1, Xb2,  nullptr, nullptr, nullptr, 512, 128, 1 };
        GP.g[1] = { Cat2, XbD1, Wct3, XbD2, nullptr, nullptr, nullptr, 512, 128, 3 };
        gemm_pair_kernel<<<dim3(NN / 32, 2), 256, 0, stream>>>(GP, Sums);
    }

    att_kernel<<<1, 64, 0, stream>>>(Sums, fc1w, fc1b, fc2w, fc2b, Att);
    final_kernel<<<(NN * 128 / 2 + 255) / 256, 256, 0, stream>>>(Xb1, Xb2, XbD1, XbD2, Att,
                                                                 convw, convb, out);
}